// Round 14
// baseline (1320.858 us; speedup 1.0000x reference)
//
#include <hip/hip_runtime.h>
#include <hip/hip_bf16.h>

#define BATCH 8
#define N1 4096
#define N2 2048
#define HID 64
#define KNN 8
#define INDIM 10

using u64 = unsigned long long;
using bf16 = __hip_bfloat16;
typedef __attribute__((ext_vector_type(8))) short short8;
typedef __attribute__((ext_vector_type(4))) float f32x4;

// Scratch in static device memory (~58 MB): d_ws size is not guaranteed.
// Every buffer is fully rewritten each call (or re-initialized by init_kernel).
__device__ __align__(256) float    g_h1[BATCH * N1 * HID];
__device__ __align__(256) float    g_h2[BATCH * N2 * HID];
__device__ __align__(256) float    g_x2n[BATCH * N1];
__device__ __align__(256) float    g_x2n2[BATCH * N2];
__device__ __align__(256) int      g_nbr[BATCH * N1 * KNN];
__device__ __align__(256) float    g_uu[BATCH * N1 * 96];
__device__ __align__(256) float    g_vv[BATCH * N1 * 96];
__device__ __align__(256) unsigned g_ek1[BATCH * N1 * HID];
__device__ __align__(256) unsigned g_ek2[BATCH * N2 * HID];
// 3-way bf16 split of h (h ~= s1+s2+s3): reused by both kNN levels (L1
// overwrites the first N2 region after L0's kNN is done).
__device__ __align__(256) bf16     g_s1[BATCH * N1 * HID];
__device__ __align__(256) bf16     g_s2[BATCH * N1 * HID];
__device__ __align__(256) bf16     g_s3[BATCH * N1 * HID];

__device__ __forceinline__ float eluf(float x) { return x > 0.f ? x : __expf(x) - 1.f; }
// order-isomorphic float->u32 encoding: a<b  <=>  enc(a)<enc(b) (unsigned)
__device__ __forceinline__ unsigned encf(float f) {
  unsigned u = __float_as_uint(f);
  return (u & 0x80000000u) ? ~u : (u | 0x80000000u);
}
__device__ __forceinline__ float decf(unsigned k) {
  unsigned u = (k & 0x80000000u) ? (k & 0x7FFFFFFFu) : ~k;
  return __uint_as_float(u);
}
// encf(-1.0f): ELU outputs are strictly > -1 => legal max-identity.
#define ENC_NEG1 0x407FFFFFu
__device__ __forceinline__ unsigned enc_safe(float v) {
  if (!(v == v)) return ENC_NEG1;
  return encf(v);
}
__device__ __forceinline__ float dec_safe(unsigned k) {
  float v = decf(k);
  if (!(v == v)) return -1.0f;
  return fminf(fmaxf(v, -3.0e38f), 3.0e38f);
}
// 3-way bf16 split: v ~= b1 + b2 + b3 (error ~2^-25 relative)
__device__ __forceinline__ void split3(float v, bf16& b1, bf16& b2, bf16& b3) {
  b1 = __float2bfloat16(v);
  float r1 = v - __bfloat162float(b1);
  b2 = __float2bfloat16(r1);
  float r2 = r1 - __bfloat162float(b2);
  b3 = __float2bfloat16(r2);
}

// ---------------- init the scatter-max accumulators --------------------------
__global__ __launch_bounds__(256) void init_kernel() {
  int t = blockIdx.x * 256 + threadIdx.x;
  uint4 z = make_uint4(ENC_NEG1, ENC_NEG1, ENC_NEG1, ENC_NEG1);
  const int n1 = BATCH * N1 * HID / 4;
  if (t < n1) ((uint4*)g_ek1)[t] = z;
  else ((uint4*)g_ek2)[t - n1] = z;
}

// ---------------- input MLP: x*norm -> 32 (elu) -> 64 (elu) + |h|^2 + splits -
__global__ __launch_bounds__(256) void input_mlp(
    const float* __restrict__ x, const float* __restrict__ norm,
    const float* __restrict__ w1g, const float* __restrict__ b1g,
    const float* __restrict__ w2g, const float* __restrict__ b2g) {
  __shared__ float sw1[320], sb1[32], sw2[2048], sb2[64], snorm[INDIM];
  int t = threadIdx.x;
  for (int q = t; q < 320; q += 256) sw1[q] = w1g[q];
  for (int q = t; q < 2048; q += 256) sw2[q] = w2g[q];
  if (t < 32) sb1[t] = b1g[t];
  if (t < 64) sb2[t] = b2g[t];
  if (t < INDIM) snorm[t] = norm[t];
  __syncthreads();
  int node = blockIdx.x * 256 + t;  // < BATCH*N1
  float xv[INDIM];
#pragma unroll
  for (int d = 0; d < INDIM; ++d)
    xv[d] = x[(size_t)node * INDIM + d] * snorm[d];
  float t1[32];
#pragma unroll
  for (int c = 0; c < 32; ++c) {
    float acc = sb1[c];
#pragma unroll
    for (int d = 0; d < INDIM; ++d) acc += xv[d] * sw1[d * 32 + c];
    t1[c] = eluf(acc);
  }
  float* hr = g_h1 + (size_t)node * HID;
  float sq = 0.f;
#pragma unroll
  for (int c = 0; c < HID; ++c) {
    float acc = sb2[c];
#pragma unroll
    for (int d = 0; d < 32; ++d) acc += t1[d] * sw2[d * HID + c];
    float v = eluf(acc);
    hr[c] = v;
    sq += v * v;
    bf16 b1v, b2v, b3v;
    split3(v, b1v, b2v, b3v);
    g_s1[(size_t)node * HID + c] = b1v;
    g_s2[(size_t)node * HID + c] = b2v;
    g_s3[(size_t)node * HID + c] = b3v;
  }
  g_x2n[node] = sq;
}

// ---------------- MFMA Gram-matrix kNN (k=8) on u64 keys ---------------------
// D = H.H^T via mfma_f32_16x16x32_bf16 with 3-way bf16 split (6 cross-terms,
// 12 MFMA per 16x16x64 tile; error ~2^-25 ~ f32 noise). Layouts (verified in
// guide): A-frag m=lane&15, k=quad*8+j; B-frag n=lane&15, k=quad*8+j (from
// row-major H); C/D col=lane&15, row=quad*4+reg. Per-lane top-8 over its col
// subset (cols == lane&15 mod 16), exact union-merge across 16 lanes via LDS.
// key = (encf(dd)<<32)|j : NaN-safe total order, tie -> lower j.
template <int LEVEL>
__global__ __launch_bounds__(256, 1) void knn_kernel() {
  constexpr int n = LEVEL ? N2 : N1;
  __shared__ u64 lm[4][16][16][KNN];  // 64 KB: [wave][row16][col16][8]
  int b = blockIdx.x & 7;             // XCD-friendly batch swizzle
  int rb = (blockIdx.x >> 3) * 64;    // block row base
  int t = threadIdx.x;
  int wv = t >> 6, lane = t & 63;
  int q = lane >> 4, c = lane & 15;
  int rbase = rb + wv * 16;           // wave's 16-row strip
  const float* __restrict__ x2b = (LEVEL ? g_x2n2 : g_x2n) + (size_t)b * n;
  const short* __restrict__ s1 = (const short*)g_s1;
  const short* __restrict__ s2 = (const short*)g_s2;
  const short* __restrict__ s3 = (const short*)g_s3;
  // A-frags: row = rbase + c (m=lane&15), chunks k = q*8 and 32+q*8
  size_t arow = ((size_t)b * n + rbase + c) * HID;
  short8 A1a = *(const short8*)(s1 + arow + q * 8);
  short8 A1b = *(const short8*)(s1 + arow + 32 + q * 8);
  short8 A2a = *(const short8*)(s2 + arow + q * 8);
  short8 A2b = *(const short8*)(s2 + arow + 32 + q * 8);
  short8 A3a = *(const short8*)(s3 + arow + q * 8);
  short8 A3b = *(const short8*)(s3 + arow + 32 + q * 8);
  // rows this lane owns in C/D: rbase + q*4 + reg
  float x2r[4];
#pragma unroll
  for (int r = 0; r < 4; ++r) x2r[r] = x2b[rbase + q * 4 + r];
  u64 best[4][KNN];
#pragma unroll
  for (int r = 0; r < 4; ++r)
#pragma unroll
    for (int p = 0; p < KNN; ++p) best[r][p] = ~0ull;
  for (int ct = 0; ct < n / 16; ++ct) {
    int cb = ct * 16 + c;  // this lane's column (n=lane&15)
    size_t bcol = ((size_t)b * n + cb) * HID;
    short8 B1a = *(const short8*)(s1 + bcol + q * 8);
    short8 B1b = *(const short8*)(s1 + bcol + 32 + q * 8);
    short8 B2a = *(const short8*)(s2 + bcol + q * 8);
    short8 B2b = *(const short8*)(s2 + bcol + 32 + q * 8);
    short8 B3a = *(const short8*)(s3 + bcol + q * 8);
    short8 B3b = *(const short8*)(s3 + bcol + 32 + q * 8);
    f32x4 acc0 = {0.f, 0.f, 0.f, 0.f};
    f32x4 acc1 = {0.f, 0.f, 0.f, 0.f};
    // two independent chains (chunk a -> acc0, chunk b -> acc1)
    acc0 = __builtin_amdgcn_mfma_f32_16x16x32_bf16(A1a, B1a, acc0, 0, 0, 0);
    acc1 = __builtin_amdgcn_mfma_f32_16x16x32_bf16(A1b, B1b, acc1, 0, 0, 0);
    acc0 = __builtin_amdgcn_mfma_f32_16x16x32_bf16(A1a, B2a, acc0, 0, 0, 0);
    acc1 = __builtin_amdgcn_mfma_f32_16x16x32_bf16(A1b, B2b, acc1, 0, 0, 0);
    acc0 = __builtin_amdgcn_mfma_f32_16x16x32_bf16(A2a, B1a, acc0, 0, 0, 0);
    acc1 = __builtin_amdgcn_mfma_f32_16x16x32_bf16(A2b, B1b, acc1, 0, 0, 0);
    acc0 = __builtin_amdgcn_mfma_f32_16x16x32_bf16(A1a, B3a, acc0, 0, 0, 0);
    acc1 = __builtin_amdgcn_mfma_f32_16x16x32_bf16(A1b, B3b, acc1, 0, 0, 0);
    acc0 = __builtin_amdgcn_mfma_f32_16x16x32_bf16(A2a, B2a, acc0, 0, 0, 0);
    acc1 = __builtin_amdgcn_mfma_f32_16x16x32_bf16(A2b, B2b, acc1, 0, 0, 0);
    acc0 = __builtin_amdgcn_mfma_f32_16x16x32_bf16(A3a, B1a, acc0, 0, 0, 0);
    acc1 = __builtin_amdgcn_mfma_f32_16x16x32_bf16(A3b, B1b, acc1, 0, 0, 0);
    float x2c = x2b[cb];
#pragma unroll
    for (int r = 0; r < 4; ++r) {
      int i = rbase + q * 4 + r;
      float dd = x2r[r] + x2c - 2.f * (acc0[r] + acc1[r]);
      u64 key = ((u64)encf(dd) << 32) | (unsigned)cb;
      if (cb != i && key < best[r][KNN - 1]) {
        u64 ck = key;
#pragma unroll
        for (int p = 0; p < KNN; ++p) {
          u64 ob = best[r][p];
          bool ex = ob < ck;
          best[r][p] = ex ? ob : ck;
          ck = ex ? ck : ob;
        }
      }
    }
  }
#pragma unroll
  for (int r = 0; r < 4; ++r)
#pragma unroll
    for (int p = 0; p < KNN; ++p) lm[wv][q * 4 + r][c][p] = best[r][p];
  __syncthreads();
  if (t < 64) {
    int wv2 = t >> 4, r16 = t & 15;
    u64 fin[KNN];
#pragma unroll
    for (int p = 0; p < KNN; ++p) fin[p] = lm[wv2][r16][0][p];
    for (int c2 = 1; c2 < 16; ++c2) {
#pragma unroll
      for (int p = 0; p < KNN; ++p) {
        u64 ck = lm[wv2][r16][c2][p];
        if (ck < fin[KNN - 1]) {
#pragma unroll
          for (int p2 = 0; p2 < KNN; ++p2) {
            u64 ob = fin[p2];
            bool ex = ob < ck;
            fin[p2] = ex ? ob : ck;
            ck = ex ? ck : ob;
          }
        }
      }
    }
    int row = rb + wv2 * 16 + r16;
    int* ob = g_nbr + ((size_t)b * n + row) * KNN;
#pragma unroll
    for (int p = 0; p < KNN; ++p) ob[p] = (int)(fin[p] & (u64)(n - 1));
  }
}

// ---------------- per-node u/v for EdgeConv layer-1 factorization ------------
// [x_d, x_s-x_d]@W1+b1 = u_d + v_s with u = x@(Wtop-Wbot)+b1, v = x@Wbot.
// block = 64 nodes x 4 col-chunks (24 cols each; chunk == wave -> uniform).
__global__ __launch_bounds__(256) void uv_kernel(int level,
                                                 const float* __restrict__ w1g,
                                                 const float* __restrict__ b1g) {
  __shared__ float sw1[128 * 96];  // 48 KB
  __shared__ float sb1[96];
  int t = threadIdx.x;
  for (int q = t; q < 128 * 96; q += 256) sw1[q] = w1g[q];
  if (t < 96) sb1[t] = b1g[t];
  __syncthreads();
  const int n = level ? N2 : N1;
  const float* h = level ? g_h2 : g_h1;
  int b = blockIdx.x & 7;
  int nl = (blockIdx.x >> 3) * 64 + (t & 63);
  int c0 = (t >> 6) * 24;  // wave-uniform chunk
  size_t node = (size_t)b * n + nl;
  const float4* h4 = (const float4*)(h + node * HID);
  float hv[HID];
#pragma unroll
  for (int q = 0; q < 16; ++q) {
    float4 vv = h4[q];
    hv[4 * q] = vv.x; hv[4 * q + 1] = vv.y; hv[4 * q + 2] = vv.z; hv[4 * q + 3] = vv.w;
  }
  float ua[24], va[24];
#pragma unroll
  for (int c = 0; c < 24; ++c) { ua[c] = 0.f; va[c] = 0.f; }
  for (int d = 0; d < HID; ++d) {
    float hd = hv[d];
    const float* wt = sw1 + d * 96 + c0;        // wave-uniform -> broadcast
    const float* wb = sw1 + (HID + d) * 96 + c0;
#pragma unroll
    for (int c = 0; c < 24; ++c) {
      ua[c] += hd * wt[c];
      va[c] += hd * wb[c];
    }
  }
  float* ur = g_uu + node * 96 + c0;
  float* vr = g_vv + node * 96 + c0;
#pragma unroll
  for (int c = 0; c < 24; ++c) {
    ur[c] = ua[c] - va[c] + sb1[c0 + c];
    vr[c] = va[c];
  }
}

// ---------------- edge messages + max scatter (wave-per-node) ----------------
// Wave owns node i; lane = output channel. Per neighbor: stage tv[96] vectors
// in LDS (forward u_i+v_j, reverse u_j+v_i), then lane-parallel 96-step FMA.
// Forward messages max-reduce in a register (1 atomic run/node); reverse
// scatters to j, skipped when the edge is mutual (identical value produced by
// j's own forward pass). One scalar accumulator per lane -> no scratch spill.
__global__ __launch_bounds__(256) void edge_kernel(int level,
                                                   const float* __restrict__ w2g,
                                                   const float* __restrict__ b2g) {
  __shared__ __align__(16) float sw2[96 * 64];  // 24 KB, [kk][o]
  __shared__ float sb2[64];
  __shared__ __align__(16) float stA[4][96], stB[4][96];  // per-wave tv vectors
  int t = threadIdx.x;
  for (int q = t; q < 96 * 64; q += 256) sw2[q] = w2g[q];
  if (t < 64) sb2[t] = b2g[t];
  __syncthreads();
  const int n = level ? N2 : N1;
  unsigned* ekey = level ? g_ek2 : g_ek1;
  int b = blockIdx.x & 7;  // XCD swizzle
  int wv = t >> 6, lane = t & 63;
  int i = (blockIdx.x >> 3) * 4 + wv;  // wave-uniform node
  const int* nbb = g_nbr + (size_t)b * n * KNN;
  const float* ub = g_uu + (size_t)b * n * 96;
  const float* vb = g_vv + (size_t)b * n * 96;
  unsigned* eb = ekey + (size_t)b * n * HID;
  float ui0 = ub[(size_t)i * 96 + lane];
  float vi0 = vb[(size_t)i * 96 + lane];
  float ui1 = 0.f, vi1 = 0.f;
  if (lane < 32) {
    ui1 = ub[(size_t)i * 96 + 64 + lane];
    vi1 = vb[(size_t)i * 96 + 64 + lane];
  }
  const float biasv = sb2[lane];
  float macc = -1.0f;
  for (int k = 0; k < KNN; ++k) {
    __syncthreads();  // protect prev iteration's tv reads before overwrite
    int j = nbb[(size_t)i * KNN + k] & (n - 1);  // wave-uniform
    bool needB = true;
#pragma unroll
    for (int k2 = 0; k2 < KNN; ++k2)
      needB = needB && ((nbb[(size_t)j * KNN + k2] & (n - 1)) != i);
    {
      float vj0 = vb[(size_t)j * 96 + lane];
      float uj0 = ub[(size_t)j * 96 + lane];
      stA[wv][lane] = eluf(ui0 + vj0);
      if (needB) stB[wv][lane] = eluf(uj0 + vi0);
      if (lane < 32) {
        float vj1 = vb[(size_t)j * 96 + 64 + lane];
        float uj1 = ub[(size_t)j * 96 + 64 + lane];
        stA[wv][64 + lane] = eluf(ui1 + vj1);
        if (needB) stB[wv][64 + lane] = eluf(uj1 + vi1);
      }
    }
    __syncthreads();  // make tv visible across lanes
    float a0 = 0.f, a1 = 0.f, b0 = 0.f, b1 = 0.f;
    if (needB) {
      for (int kk = 0; kk < 96; kk += 4) {
        float4 ta = *(const float4*)&stA[wv][kk];
        float4 tb = *(const float4*)&stB[wv][kk];
        float w0 = sw2[(kk + 0) * 64 + lane];
        float w1 = sw2[(kk + 1) * 64 + lane];
        float w2v = sw2[(kk + 2) * 64 + lane];
        float w3 = sw2[(kk + 3) * 64 + lane];
        a0 += ta.x * w0 + ta.y * w1;
        a1 += ta.z * w2v + ta.w * w3;
        b0 += tb.x * w0 + tb.y * w1;
        b1 += tb.z * w2v + tb.w * w3;
      }
      atomicMax(&eb[(size_t)j * HID + lane],
                enc_safe(eluf(biasv + b0 + b1)));
    } else {
      for (int kk = 0; kk < 96; kk += 4) {
        float4 ta = *(const float4*)&stA[wv][kk];
        float w0 = sw2[(kk + 0) * 64 + lane];
        float w1 = sw2[(kk + 1) * 64 + lane];
        float w2v = sw2[(kk + 2) * 64 + lane];
        float w3 = sw2[(kk + 3) * 64 + lane];
        a0 += ta.x * w0 + ta.y * w1;
        a1 += ta.z * w2v + ta.w * w3;
      }
    }
    macc = fmaxf(macc, eluf(biasv + a0 + a1));
  }
  atomicMax(&eb[(size_t)i * HID + lane], enc_safe(macc));
}

// ---------------- pairwise max pool + norms + bf16 splits --------------------
__global__ __launch_bounds__(256) void pool_kernel() {
  int node = blockIdx.x * 256 + threadIdx.x;  // < BATCH*N2
  int b = node >> 11;
  int m = node & (N2 - 1);
  const unsigned* e = g_ek1 + ((size_t)b * N1 + 2 * m) * HID;
  float* hr = g_h2 + (size_t)node * HID;
  float sq = 0.f;
#pragma unroll
  for (int d = 0; d < HID; ++d) {
    float mx = fmaxf(dec_safe(e[d]), dec_safe(e[HID + d]));
    hr[d] = mx;
    sq += mx * mx;
    bf16 b1v, b2v, b3v;
    split3(mx, b1v, b2v, b3v);
    g_s1[(size_t)node * HID + d] = b1v;
    g_s2[(size_t)node * HID + d] = b2v;
    g_s3[(size_t)node * HID + d] = b3v;
  }
  g_x2n2[node] = sq;
}

// ---------------- global max + output MLP -> FLOAT32 output ------------------
__global__ __launch_bounds__(64) void final_kernel(
    const float* __restrict__ wo1, const float* __restrict__ bo1,
    const float* __restrict__ wo2, const float* __restrict__ bo2,
    const float* __restrict__ wo3, const float* __restrict__ bo3,
    float* __restrict__ out) {
  __shared__ float g[HID];
  __shared__ float o1s[HID];
  __shared__ float o2s[32];
  int b = blockIdx.x;
  int t = threadIdx.x;  // 0..63
  const unsigned* e = g_ek2 + (size_t)b * N2 * HID;
  unsigned mk = 0u;
  for (int m = 0; m < N2; ++m) {
    unsigned q = e[(size_t)m * HID + t];
    mk = q > mk ? q : mk;
  }
  g[t] = dec_safe(mk);
  __syncthreads();
  {
    float a1 = bo1[t];
    for (int d = 0; d < HID; ++d) a1 += g[d] * wo1[d * HID + t];
    o1s[t] = eluf(a1);
  }
  __syncthreads();
  if (t < 32) {
    float a2 = bo2[t];
    for (int d = 0; d < HID; ++d) a2 += o1s[d] * wo2[d * 32 + t];
    o2s[t] = eluf(a2);
  }
  __syncthreads();
  if (t == 0) {
    float acc0 = bo3[0];
    float acc1 = bo3[1];
    for (int d = 0; d < 32; ++d) {
      acc0 += o2s[d] * wo3[d * 2 + 0];
      acc1 += o2s[d] * wo3[d * 2 + 1];
    }
    float met = fmaxf(acc0, 0.f) + log1pf(expf(-fabsf(acc0)));      // softplus
    float phi = 3.14159265358979f * (2.f / (1.f + expf(-acc1)) - 1.f);
    out[b * 2 + 0] = met;
    out[b * 2 + 1] = phi;
  }
}

extern "C" void kernel_launch(void* const* d_in, const int* in_sizes, int n_in,
                              void* d_out, int out_size, void* d_ws,
                              size_t ws_size, hipStream_t stream) {
  const float* x     = (const float*)d_in[0];
  const float* dnorm = (const float*)d_in[1];
  const float* w_in1 = (const float*)d_in[2];
  const float* b_in1 = (const float*)d_in[3];
  const float* w_in2 = (const float*)d_in[4];
  const float* b_in2 = (const float*)d_in[5];
  const float* w_c1a = (const float*)d_in[6];
  const float* b_c1a = (const float*)d_in[7];
  const float* w_c1b = (const float*)d_in[8];
  const float* b_c1b = (const float*)d_in[9];
  const float* w_c2a = (const float*)d_in[10];
  const float* b_c2a = (const float*)d_in[11];
  const float* w_c2b = (const float*)d_in[12];
  const float* b_c2b = (const float*)d_in[13];
  const float* w_o1  = (const float*)d_in[14];
  const float* b_o1  = (const float*)d_in[15];
  const float* w_o2  = (const float*)d_in[16];
  const float* b_o2  = (const float*)d_in[17];
  const float* w_o3  = (const float*)d_in[18];
  const float* b_o3  = (const float*)d_in[19];

  init_kernel<<<(BATCH * N1 * HID + BATCH * N2 * HID) / 4 / 256, 256, 0,
                stream>>>();
  input_mlp<<<BATCH * N1 / 256, 256, 0, stream>>>(x, dnorm, w_in1, b_in1,
                                                  w_in2, b_in2);
  knn_kernel<0><<<8 * (N1 / 64), 256, 0, stream>>>();
  uv_kernel<<<8 * (N1 / 64), 256, 0, stream>>>(0, w_c1a, b_c1a);
  edge_kernel<<<8 * (N1 / 4), 256, 0, stream>>>(0, w_c1b, b_c1b);
  pool_kernel<<<BATCH * N2 / 256, 256, 0, stream>>>();
  knn_kernel<1><<<8 * (N2 / 64), 256, 0, stream>>>();
  uv_kernel<<<8 * (N2 / 64), 256, 0, stream>>>(1, w_c2a, b_c2a);
  edge_kernel<<<8 * (N2 / 4), 256, 0, stream>>>(1, w_c2b, b_c2b);
  final_kernel<<<BATCH, 64, 0, stream>>>(w_o1, b_o1, w_o2, b_o2, w_o3, b_o3,
                                         (float*)d_out);
}

// Round 15
// 1128.099 us; speedup vs baseline: 1.1709x; 1.1709x over previous
//
#include <hip/hip_runtime.h>
#include <hip/hip_bf16.h>

#define BATCH 8
#define N1 4096
#define N2 2048
#define HID 64
#define KNN 8
#define INDIM 10

using u64 = unsigned long long;
using bf16 = __hip_bfloat16;
typedef __attribute__((ext_vector_type(8))) short short8;
typedef __attribute__((ext_vector_type(4))) float f32x4;

// Scratch in static device memory (~58 MB): d_ws size is not guaranteed.
// Every buffer is fully rewritten each call (or re-initialized by init_kernel).
__device__ __align__(256) float    g_h1[BATCH * N1 * HID];
__device__ __align__(256) float    g_h2[BATCH * N2 * HID];
__device__ __align__(256) float    g_x2n[BATCH * N1];
__device__ __align__(256) float    g_x2n2[BATCH * N2];
__device__ __align__(256) int      g_nbr[BATCH * N1 * KNN];
__device__ __align__(256) float    g_uu[BATCH * N1 * 96];
__device__ __align__(256) float    g_vv[BATCH * N1 * 96];
__device__ __align__(256) unsigned g_ek1[BATCH * N1 * HID];
__device__ __align__(256) unsigned g_ek2[BATCH * N2 * HID];
// 3-way bf16 split of h in MFMA FRAGMENT-MAJOR layout:
// [tile16][chunk(2)][q(4)][c(16)][j(8)] shorts -- lane q*16+c reads its 16B
// fragment at base+lane*16 => fully coalesced 1KB loads (r14's row-major
// layout made every B-frag load a stride-128B scatter: the 520us cost).
// Node i=tile*16+c, k=chunk*32+q*8+j. Reused by both kNN levels.
__device__ __align__(256) short    g_f1[BATCH * N1 * HID];
__device__ __align__(256) short    g_f2[BATCH * N1 * HID];
__device__ __align__(256) short    g_f3[BATCH * N1 * HID];

__device__ __forceinline__ float eluf(float x) { return x > 0.f ? x : __expf(x) - 1.f; }
// order-isomorphic float->u32 encoding: a<b  <=>  enc(a)<enc(b) (unsigned)
__device__ __forceinline__ unsigned encf(float f) {
  unsigned u = __float_as_uint(f);
  return (u & 0x80000000u) ? ~u : (u | 0x80000000u);
}
__device__ __forceinline__ float decf(unsigned k) {
  unsigned u = (k & 0x80000000u) ? (k & 0x7FFFFFFFu) : ~k;
  return __uint_as_float(u);
}
// encf(-1.0f): ELU outputs are strictly > -1 => legal max-identity.
#define ENC_NEG1 0x407FFFFFu
__device__ __forceinline__ unsigned enc_safe(float v) {
  if (!(v == v)) return ENC_NEG1;
  return encf(v);
}
__device__ __forceinline__ float dec_safe(unsigned k) {
  float v = decf(k);
  if (!(v == v)) return -1.0f;
  return fminf(fmaxf(v, -3.0e38f), 3.0e38f);
}
// 3-way bf16 split: v ~= b1 + b2 + b3 (error ~2^-25 relative)
__device__ __forceinline__ void split3(float v, short& b1, short& b2, short& b3) {
  bf16 x1 = __float2bfloat16(v);
  float r1 = v - __bfloat162float(x1);
  bf16 x2 = __float2bfloat16(r1);
  float r2 = r1 - __bfloat162float(x2);
  bf16 x3 = __float2bfloat16(r2);
  b1 = *(short*)&x1; b2 = *(short*)&x2; b3 = *(short*)&x3;
}
// write one node's 64 splits into fragment-major layout
__device__ __forceinline__ void store_frags(int node, const short* s1,
                                            const short* s2, const short* s3) {
  // global tile = node>>4 (works for both levels), c = node&15
  size_t tb = ((size_t)(node >> 4)) * 1024 + (node & 15) * 8;
#pragma unroll
  for (int chunk = 0; chunk < 2; ++chunk) {
#pragma unroll
    for (int q = 0; q < 4; ++q) {
      size_t a = tb + chunk * 512 + q * 128;
      int k = chunk * 32 + q * 8;
      *(short8*)(g_f1 + a) = *(const short8*)(s1 + k);
      *(short8*)(g_f2 + a) = *(const short8*)(s2 + k);
      *(short8*)(g_f3 + a) = *(const short8*)(s3 + k);
    }
  }
}

// ---------------- init the scatter-max accumulators --------------------------
__global__ __launch_bounds__(256) void init_kernel() {
  int t = blockIdx.x * 256 + threadIdx.x;
  uint4 z = make_uint4(ENC_NEG1, ENC_NEG1, ENC_NEG1, ENC_NEG1);
  const int n1 = BATCH * N1 * HID / 4;
  if (t < n1) ((uint4*)g_ek1)[t] = z;
  else ((uint4*)g_ek2)[t - n1] = z;
}

// ---------------- input MLP: x*norm -> 32 (elu) -> 64 (elu) + |h|^2 + splits -
__global__ __launch_bounds__(256) void input_mlp(
    const float* __restrict__ x, const float* __restrict__ norm,
    const float* __restrict__ w1g, const float* __restrict__ b1g,
    const float* __restrict__ w2g, const float* __restrict__ b2g) {
  __shared__ float sw1[320], sb1[32], sw2[2048], sb2[64], snorm[INDIM];
  int t = threadIdx.x;
  for (int q = t; q < 320; q += 256) sw1[q] = w1g[q];
  for (int q = t; q < 2048; q += 256) sw2[q] = w2g[q];
  if (t < 32) sb1[t] = b1g[t];
  if (t < 64) sb2[t] = b2g[t];
  if (t < INDIM) snorm[t] = norm[t];
  __syncthreads();
  int node = blockIdx.x * 256 + t;  // < BATCH*N1
  float xv[INDIM];
#pragma unroll
  for (int d = 0; d < INDIM; ++d)
    xv[d] = x[(size_t)node * INDIM + d] * snorm[d];
  float t1[32];
#pragma unroll
  for (int c = 0; c < 32; ++c) {
    float acc = sb1[c];
#pragma unroll
    for (int d = 0; d < INDIM; ++d) acc += xv[d] * sw1[d * 32 + c];
    t1[c] = eluf(acc);
  }
  float* hr = g_h1 + (size_t)node * HID;
  float sq = 0.f;
  short s1l[HID], s2l[HID], s3l[HID];
#pragma unroll
  for (int c = 0; c < HID; ++c) {
    float acc = sb2[c];
#pragma unroll
    for (int d = 0; d < 32; ++d) acc += t1[d] * sw2[d * HID + c];
    float v = eluf(acc);
    hr[c] = v;
    sq += v * v;
    split3(v, s1l[c], s2l[c], s3l[c]);
  }
  store_frags(node, s1l, s2l, s3l);
  g_x2n[node] = sq;
}

// ---------------- MFMA Gram-matrix kNN (k=8) on u64 keys ---------------------
// D = H.H^T via mfma_f32_16x16x32_bf16 with 3-way bf16 split (6 cross-terms,
// 12 MFMA per 16x16x64 tile; error ~2^-25 ~ f32 noise). Fragment-major
// storage makes every A/B frag load a coalesced 1KB vmem op. Layouts:
// A-frag m=lane&15, k=quad*8+j; B same; C/D col=lane&15, row=quad*4+reg.
// Per-lane top-8 over its col subset, exact union-merge across 16 lanes via
// LDS. key = (encf(dd)<<32)|j : NaN-safe total order, tie -> lower j.
template <int LEVEL>
__global__ __launch_bounds__(256, 1) void knn_kernel() {
  constexpr int n = LEVEL ? N2 : N1;
  __shared__ u64 lm[4][16][16][KNN];  // 64 KB: [wave][row16][col16][8]
  int b = blockIdx.x & 7;             // XCD-friendly batch swizzle
  int rb = (blockIdx.x >> 3) * 64;    // block row base
  int t = threadIdx.x;
  int wv = t >> 6, lane = t & 63;
  int q = lane >> 4, c = lane & 15;
  int rbase = rb + wv * 16;           // wave's 16-row strip
  const float* __restrict__ x2b = (LEVEL ? g_x2n2 : g_x2n) + (size_t)b * n;
  // fragment-major bases: tile index is global (b*n+i)>>4
  size_t abase = ((size_t)((b * n + rbase) >> 4)) * 1024 + lane * 8;
  short8 A1a = *(const short8*)(g_f1 + abase);
  short8 A1b = *(const short8*)(g_f1 + abase + 512);
  short8 A2a = *(const short8*)(g_f2 + abase);
  short8 A2b = *(const short8*)(g_f2 + abase + 512);
  short8 A3a = *(const short8*)(g_f3 + abase);
  short8 A3b = *(const short8*)(g_f3 + abase + 512);
  // rows this lane owns in C/D: rbase + q*4 + reg
  float x2r[4];
#pragma unroll
  for (int r = 0; r < 4; ++r) x2r[r] = x2b[rbase + q * 4 + r];
  u64 best[4][KNN];
#pragma unroll
  for (int r = 0; r < 4; ++r)
#pragma unroll
    for (int p = 0; p < KNN; ++p) best[r][p] = ~0ull;
  size_t bstep = 1024;
  size_t bb = ((size_t)(b * n) >> 4) * 1024 + lane * 8;
  for (int ct = 0; ct < n / 16; ++ct, bb += bstep) {
    int cb = ct * 16 + c;  // this lane's column (n=lane&15)
    short8 B1a = *(const short8*)(g_f1 + bb);
    short8 B1b = *(const short8*)(g_f1 + bb + 512);
    short8 B2a = *(const short8*)(g_f2 + bb);
    short8 B2b = *(const short8*)(g_f2 + bb + 512);
    short8 B3a = *(const short8*)(g_f3 + bb);
    short8 B3b = *(const short8*)(g_f3 + bb + 512);
    f32x4 acc0 = {0.f, 0.f, 0.f, 0.f};
    f32x4 acc1 = {0.f, 0.f, 0.f, 0.f};
    // two independent chains (chunk a -> acc0, chunk b -> acc1)
    acc0 = __builtin_amdgcn_mfma_f32_16x16x32_bf16(A1a, B1a, acc0, 0, 0, 0);
    acc1 = __builtin_amdgcn_mfma_f32_16x16x32_bf16(A1b, B1b, acc1, 0, 0, 0);
    acc0 = __builtin_amdgcn_mfma_f32_16x16x32_bf16(A1a, B2a, acc0, 0, 0, 0);
    acc1 = __builtin_amdgcn_mfma_f32_16x16x32_bf16(A1b, B2b, acc1, 0, 0, 0);
    acc0 = __builtin_amdgcn_mfma_f32_16x16x32_bf16(A2a, B1a, acc0, 0, 0, 0);
    acc1 = __builtin_amdgcn_mfma_f32_16x16x32_bf16(A2b, B1b, acc1, 0, 0, 0);
    acc0 = __builtin_amdgcn_mfma_f32_16x16x32_bf16(A1a, B3a, acc0, 0, 0, 0);
    acc1 = __builtin_amdgcn_mfma_f32_16x16x32_bf16(A1b, B3b, acc1, 0, 0, 0);
    acc0 = __builtin_amdgcn_mfma_f32_16x16x32_bf16(A2a, B2a, acc0, 0, 0, 0);
    acc1 = __builtin_amdgcn_mfma_f32_16x16x32_bf16(A2b, B2b, acc1, 0, 0, 0);
    acc0 = __builtin_amdgcn_mfma_f32_16x16x32_bf16(A3a, B1a, acc0, 0, 0, 0);
    acc1 = __builtin_amdgcn_mfma_f32_16x16x32_bf16(A3b, B1b, acc1, 0, 0, 0);
    float x2c = x2b[cb];
#pragma unroll
    for (int r = 0; r < 4; ++r) {
      int i = rbase + q * 4 + r;
      float dd = x2r[r] + x2c - 2.f * (acc0[r] + acc1[r]);
      u64 key = ((u64)encf(dd) << 32) | (unsigned)cb;
      if (cb != i && key < best[r][KNN - 1]) {
        u64 ck = key;
#pragma unroll
        for (int p = 0; p < KNN; ++p) {
          u64 ob = best[r][p];
          bool ex = ob < ck;
          best[r][p] = ex ? ob : ck;
          ck = ex ? ck : ob;
        }
      }
    }
  }
#pragma unroll
  for (int r = 0; r < 4; ++r)
#pragma unroll
    for (int p = 0; p < KNN; ++p) lm[wv][q * 4 + r][c][p] = best[r][p];
  __syncthreads();
  if (t < 64) {
    int wv2 = t >> 4, r16 = t & 15;
    u64 fin[KNN];
#pragma unroll
    for (int p = 0; p < KNN; ++p) fin[p] = lm[wv2][r16][0][p];
    for (int c2 = 1; c2 < 16; ++c2) {
#pragma unroll
      for (int p = 0; p < KNN; ++p) {
        u64 ck = lm[wv2][r16][c2][p];
        if (ck < fin[KNN - 1]) {
#pragma unroll
          for (int p2 = 0; p2 < KNN; ++p2) {
            u64 ob = fin[p2];
            bool ex = ob < ck;
            fin[p2] = ex ? ob : ck;
            ck = ex ? ck : ob;
          }
        }
      }
    }
    int row = rb + wv2 * 16 + r16;
    int* ob = g_nbr + ((size_t)b * n + row) * KNN;
#pragma unroll
    for (int p = 0; p < KNN; ++p) ob[p] = (int)(fin[p] & (u64)(n - 1));
  }
}

// ---------------- per-node u/v for EdgeConv layer-1 factorization ------------
// [x_d, x_s-x_d]@W1+b1 = u_d + v_s with u = x@(Wtop-Wbot)+b1, v = x@Wbot.
// block = 64 nodes x 4 col-chunks (24 cols each; chunk == wave -> uniform).
__global__ __launch_bounds__(256) void uv_kernel(int level,
                                                 const float* __restrict__ w1g,
                                                 const float* __restrict__ b1g) {
  __shared__ float sw1[128 * 96];  // 48 KB
  __shared__ float sb1[96];
  int t = threadIdx.x;
  for (int q = t; q < 128 * 96; q += 256) sw1[q] = w1g[q];
  if (t < 96) sb1[t] = b1g[t];
  __syncthreads();
  const int n = level ? N2 : N1;
  const float* h = level ? g_h2 : g_h1;
  int b = blockIdx.x & 7;
  int nl = (blockIdx.x >> 3) * 64 + (t & 63);
  int c0 = (t >> 6) * 24;  // wave-uniform chunk
  size_t node = (size_t)b * n + nl;
  const float4* h4 = (const float4*)(h + node * HID);
  float hv[HID];
#pragma unroll
  for (int q = 0; q < 16; ++q) {
    float4 vv = h4[q];
    hv[4 * q] = vv.x; hv[4 * q + 1] = vv.y; hv[4 * q + 2] = vv.z; hv[4 * q + 3] = vv.w;
  }
  float ua[24], va[24];
#pragma unroll
  for (int c = 0; c < 24; ++c) { ua[c] = 0.f; va[c] = 0.f; }
  for (int d = 0; d < HID; ++d) {
    float hd = hv[d];
    const float* wt = sw1 + d * 96 + c0;        // wave-uniform -> broadcast
    const float* wb = sw1 + (HID + d) * 96 + c0;
#pragma unroll
    for (int c = 0; c < 24; ++c) {
      ua[c] += hd * wt[c];
      va[c] += hd * wb[c];
    }
  }
  float* ur = g_uu + node * 96 + c0;
  float* vr = g_vv + node * 96 + c0;
#pragma unroll
  for (int c = 0; c < 24; ++c) {
    ur[c] = ua[c] - va[c] + sb1[c0 + c];
    vr[c] = va[c];
  }
}

// ---------------- edge messages + max scatter (wave-per-node) ----------------
// Wave owns node i; lane = output channel. Per neighbor: stage tv[96] vectors
// in LDS (forward u_i+v_j, reverse u_j+v_i), then lane-parallel 96-step FMA.
// Forward messages max-reduce in a register (1 atomic run/node); reverse
// scatters to j, skipped when the edge is mutual (identical value produced by
// j's own forward pass). One scalar accumulator per lane -> no scratch spill.
__global__ __launch_bounds__(256) void edge_kernel(int level,
                                                   const float* __restrict__ w2g,
                                                   const float* __restrict__ b2g) {
  __shared__ __align__(16) float sw2[96 * 64];  // 24 KB, [kk][o]
  __shared__ float sb2[64];
  __shared__ __align__(16) float stA[4][96], stB[4][96];  // per-wave tv vectors
  int t = threadIdx.x;
  for (int q = t; q < 96 * 64; q += 256) sw2[q] = w2g[q];
  if (t < 64) sb2[t] = b2g[t];
  __syncthreads();
  const int n = level ? N2 : N1;
  unsigned* ekey = level ? g_ek2 : g_ek1;
  int b = blockIdx.x & 7;  // XCD swizzle
  int wv = t >> 6, lane = t & 63;
  int i = (blockIdx.x >> 3) * 4 + wv;  // wave-uniform node
  const int* nbb = g_nbr + (size_t)b * n * KNN;
  const float* ub = g_uu + (size_t)b * n * 96;
  const float* vb = g_vv + (size_t)b * n * 96;
  unsigned* eb = ekey + (size_t)b * n * HID;
  float ui0 = ub[(size_t)i * 96 + lane];
  float vi0 = vb[(size_t)i * 96 + lane];
  float ui1 = 0.f, vi1 = 0.f;
  if (lane < 32) {
    ui1 = ub[(size_t)i * 96 + 64 + lane];
    vi1 = vb[(size_t)i * 96 + 64 + lane];
  }
  const float biasv = sb2[lane];
  float macc = -1.0f;
  for (int k = 0; k < KNN; ++k) {
    __syncthreads();  // protect prev iteration's tv reads before overwrite
    int j = nbb[(size_t)i * KNN + k] & (n - 1);  // wave-uniform
    bool needB = true;
#pragma unroll
    for (int k2 = 0; k2 < KNN; ++k2)
      needB = needB && ((nbb[(size_t)j * KNN + k2] & (n - 1)) != i);
    {
      float vj0 = vb[(size_t)j * 96 + lane];
      float uj0 = ub[(size_t)j * 96 + lane];
      stA[wv][lane] = eluf(ui0 + vj0);
      if (needB) stB[wv][lane] = eluf(uj0 + vi0);
      if (lane < 32) {
        float vj1 = vb[(size_t)j * 96 + 64 + lane];
        float uj1 = ub[(size_t)j * 96 + 64 + lane];
        stA[wv][64 + lane] = eluf(ui1 + vj1);
        if (needB) stB[wv][64 + lane] = eluf(uj1 + vi1);
      }
    }
    __syncthreads();  // make tv visible across lanes
    float a0 = 0.f, a1 = 0.f, b0 = 0.f, b1 = 0.f;
    if (needB) {
      for (int kk = 0; kk < 96; kk += 4) {
        float4 ta = *(const float4*)&stA[wv][kk];
        float4 tb = *(const float4*)&stB[wv][kk];
        float w0 = sw2[(kk + 0) * 64 + lane];
        float w1 = sw2[(kk + 1) * 64 + lane];
        float w2v = sw2[(kk + 2) * 64 + lane];
        float w3 = sw2[(kk + 3) * 64 + lane];
        a0 += ta.x * w0 + ta.y * w1;
        a1 += ta.z * w2v + ta.w * w3;
        b0 += tb.x * w0 + tb.y * w1;
        b1 += tb.z * w2v + tb.w * w3;
      }
      atomicMax(&eb[(size_t)j * HID + lane],
                enc_safe(eluf(biasv + b0 + b1)));
    } else {
      for (int kk = 0; kk < 96; kk += 4) {
        float4 ta = *(const float4*)&stA[wv][kk];
        float w0 = sw2[(kk + 0) * 64 + lane];
        float w1 = sw2[(kk + 1) * 64 + lane];
        float w2v = sw2[(kk + 2) * 64 + lane];
        float w3 = sw2[(kk + 3) * 64 + lane];
        a0 += ta.x * w0 + ta.y * w1;
        a1 += ta.z * w2v + ta.w * w3;
      }
    }
    macc = fmaxf(macc, eluf(biasv + a0 + a1));
  }
  atomicMax(&eb[(size_t)i * HID + lane], enc_safe(macc));
}

// ---------------- pairwise max pool + norms + bf16 splits --------------------
__global__ __launch_bounds__(256) void pool_kernel() {
  int node = blockIdx.x * 256 + threadIdx.x;  // < BATCH*N2
  int b = node >> 11;
  int m = node & (N2 - 1);
  const unsigned* e = g_ek1 + ((size_t)b * N1 + 2 * m) * HID;
  float* hr = g_h2 + (size_t)node * HID;
  float sq = 0.f;
  short s1l[HID], s2l[HID], s3l[HID];
#pragma unroll
  for (int d = 0; d < HID; ++d) {
    float mx = fmaxf(dec_safe(e[d]), dec_safe(e[HID + d]));
    hr[d] = mx;
    sq += mx * mx;
    split3(mx, s1l[d], s2l[d], s3l[d]);
  }
  store_frags(node, s1l, s2l, s3l);
  g_x2n2[node] = sq;
}

// ---------------- global max + output MLP -> FLOAT32 output ------------------
__global__ __launch_bounds__(64) void final_kernel(
    const float* __restrict__ wo1, const float* __restrict__ bo1,
    const float* __restrict__ wo2, const float* __restrict__ bo2,
    const float* __restrict__ wo3, const float* __restrict__ bo3,
    float* __restrict__ out) {
  __shared__ float g[HID];
  __shared__ float o1s[HID];
  __shared__ float o2s[32];
  int b = blockIdx.x;
  int t = threadIdx.x;  // 0..63
  const unsigned* e = g_ek2 + (size_t)b * N2 * HID;
  unsigned mk = 0u;
  for (int m = 0; m < N2; ++m) {
    unsigned q = e[(size_t)m * HID + t];
    mk = q > mk ? q : mk;
  }
  g[t] = dec_safe(mk);
  __syncthreads();
  {
    float a1 = bo1[t];
    for (int d = 0; d < HID; ++d) a1 += g[d] * wo1[d * HID + t];
    o1s[t] = eluf(a1);
  }
  __syncthreads();
  if (t < 32) {
    float a2 = bo2[t];
    for (int d = 0; d < HID; ++d) a2 += o1s[d] * wo2[d * 32 + t];
    o2s[t] = eluf(a2);
  }
  __syncthreads();
  if (t == 0) {
    float acc0 = bo3[0];
    float acc1 = bo3[1];
    for (int d = 0; d < 32; ++d) {
      acc0 += o2s[d] * wo3[d * 2 + 0];
      acc1 += o2s[d] * wo3[d * 2 + 1];
    }
    float met = fmaxf(acc0, 0.f) + log1pf(expf(-fabsf(acc0)));      // softplus
    float phi = 3.14159265358979f * (2.f / (1.f + expf(-acc1)) - 1.f);
    out[b * 2 + 0] = met;
    out[b * 2 + 1] = phi;
  }
}

extern "C" void kernel_launch(void* const* d_in, const int* in_sizes, int n_in,
                              void* d_out, int out_size, void* d_ws,
                              size_t ws_size, hipStream_t stream) {
  const float* x     = (const float*)d_in[0];
  const float* dnorm = (const float*)d_in[1];
  const float* w_in1 = (const float*)d_in[2];
  const float* b_in1 = (const float*)d_in[3];
  const float* w_in2 = (const float*)d_in[4];
  const float* b_in2 = (const float*)d_in[5];
  const float* w_c1a = (const float*)d_in[6];
  const float* b_c1a = (const float*)d_in[7];
  const float* w_c1b = (const float*)d_in[8];
  const float* b_c1b = (const float*)d_in[9];
  const float* w_c2a = (const float*)d_in[10];
  const float* b_c2a = (const float*)d_in[11];
  const float* w_c2b = (const float*)d_in[12];
  const float* b_c2b = (const float*)d_in[13];
  const float* w_o1  = (const float*)d_in[14];
  const float* b_o1  = (const float*)d_in[15];
  const float* w_o2  = (const float*)d_in[16];
  const float* b_o2  = (const float*)d_in[17];
  const float* w_o3  = (const float*)d_in[18];
  const float* b_o3  = (const float*)d_in[19];

  init_kernel<<<(BATCH * N1 * HID + BATCH * N2 * HID) / 4 / 256, 256, 0,
                stream>>>();
  input_mlp<<<BATCH * N1 / 256, 256, 0, stream>>>(x, dnorm, w_in1, b_in1,
                                                  w_in2, b_in2);
  knn_kernel<0><<<8 * (N1 / 64), 256, 0, stream>>>();
  uv_kernel<<<8 * (N1 / 64), 256, 0, stream>>>(0, w_c1a, b_c1a);
  edge_kernel<<<8 * (N1 / 4), 256, 0, stream>>>(0, w_c1b, b_c1b);
  pool_kernel<<<BATCH * N2 / 256, 256, 0, stream>>>();
  knn_kernel<1><<<8 * (N2 / 64), 256, 0, stream>>>();
  uv_kernel<<<8 * (N2 / 64), 256, 0, stream>>>(1, w_c2a, b_c2a);
  edge_kernel<<<8 * (N2 / 4), 256, 0, stream>>>(1, w_c2b, b_c2b);
  final_kernel<<<BATCH, 64, 0, stream>>>(w_o1, b_o1, w_o2, b_o2, w_o3, b_o3,
                                         (float*)d_out);
}

// Round 16
// 880.342 us; speedup vs baseline: 1.5004x; 1.2814x over previous
//
#include <hip/hip_runtime.h>
#include <hip/hip_bf16.h>

#define BATCH 8
#define N1 4096
#define N2 2048
#define HID 64
#define KNN 8
#define INDIM 10

using u64 = unsigned long long;
using bf16 = __hip_bfloat16;
typedef __attribute__((ext_vector_type(8))) short short8;
typedef __attribute__((ext_vector_type(4))) float f32x4;

// Scratch in static device memory (~58 MB): d_ws size is not guaranteed.
// Every buffer is fully rewritten each call (or re-initialized by init_kernel).
__device__ __align__(256) float    g_h1[BATCH * N1 * HID];
__device__ __align__(256) float    g_h2[BATCH * N2 * HID];
__device__ __align__(256) float    g_x2n[BATCH * N1];
__device__ __align__(256) float    g_x2n2[BATCH * N2];
__device__ __align__(256) int      g_nbr[BATCH * N1 * KNN];
__device__ __align__(256) float    g_uu[BATCH * N1 * 96];
__device__ __align__(256) float    g_vv[BATCH * N1 * 96];
__device__ __align__(256) unsigned g_ek1[BATCH * N1 * HID];
__device__ __align__(256) unsigned g_ek2[BATCH * N2 * HID];
// 3-way bf16 split of h in MFMA FRAGMENT-MAJOR layout:
// [tile16][chunk(2)][q(4)][c(16)][j(8)] shorts -- lane q*16+c reads its 16B
// fragment at base+lane*16 => fully coalesced 1KB loads.
// Node i=tile*16+c, k=chunk*32+q*8+j. Reused by both kNN levels.
__device__ __align__(256) short    g_f1[BATCH * N1 * HID];
__device__ __align__(256) short    g_f2[BATCH * N1 * HID];
__device__ __align__(256) short    g_f3[BATCH * N1 * HID];

__device__ __forceinline__ float eluf(float x) { return x > 0.f ? x : __expf(x) - 1.f; }
// order-isomorphic float->u32 encoding: a<b  <=>  enc(a)<enc(b) (unsigned)
__device__ __forceinline__ unsigned encf(float f) {
  unsigned u = __float_as_uint(f);
  return (u & 0x80000000u) ? ~u : (u | 0x80000000u);
}
__device__ __forceinline__ float decf(unsigned k) {
  unsigned u = (k & 0x80000000u) ? (k & 0x7FFFFFFFu) : ~k;
  return __uint_as_float(u);
}
// encf(-1.0f): ELU outputs are strictly > -1 => legal max-identity.
#define ENC_NEG1 0x407FFFFFu
__device__ __forceinline__ unsigned enc_safe(float v) {
  if (!(v == v)) return ENC_NEG1;
  return encf(v);
}
__device__ __forceinline__ float dec_safe(unsigned k) {
  float v = decf(k);
  if (!(v == v)) return -1.0f;
  return fminf(fmaxf(v, -3.0e38f), 3.0e38f);
}
// 3-way bf16 split: v ~= b1 + b2 + b3 (error ~2^-25 relative)
__device__ __forceinline__ void split3(float v, short& b1, short& b2, short& b3) {
  bf16 x1 = __float2bfloat16(v);
  float r1 = v - __bfloat162float(x1);
  bf16 x2 = __float2bfloat16(r1);
  float r2 = r1 - __bfloat162float(x2);
  bf16 x3 = __float2bfloat16(r2);
  b1 = *(short*)&x1; b2 = *(short*)&x2; b3 = *(short*)&x3;
}
// write one node's 64 splits into fragment-major layout
__device__ __forceinline__ void store_frags(int node, const short* s1,
                                            const short* s2, const short* s3) {
  size_t tb = ((size_t)(node >> 4)) * 1024 + (node & 15) * 8;
#pragma unroll
  for (int chunk = 0; chunk < 2; ++chunk) {
#pragma unroll
    for (int q = 0; q < 4; ++q) {
      size_t a = tb + chunk * 512 + q * 128;
      int k = chunk * 32 + q * 8;
      *(short8*)(g_f1 + a) = *(const short8*)(s1 + k);
      *(short8*)(g_f2 + a) = *(const short8*)(s2 + k);
      *(short8*)(g_f3 + a) = *(const short8*)(s3 + k);
    }
  }
}

// ---------------- init the scatter-max accumulators --------------------------
__global__ __launch_bounds__(256) void init_kernel() {
  int t = blockIdx.x * 256 + threadIdx.x;
  uint4 z = make_uint4(ENC_NEG1, ENC_NEG1, ENC_NEG1, ENC_NEG1);
  const int n1 = BATCH * N1 * HID / 4;
  if (t < n1) ((uint4*)g_ek1)[t] = z;
  else ((uint4*)g_ek2)[t - n1] = z;
}

// ---------------- input MLP: x*norm -> 32 (elu) -> 64 (elu) + |h|^2 + splits -
__global__ __launch_bounds__(256) void input_mlp(
    const float* __restrict__ x, const float* __restrict__ norm,
    const float* __restrict__ w1g, const float* __restrict__ b1g,
    const float* __restrict__ w2g, const float* __restrict__ b2g) {
  __shared__ float sw1[320], sb1[32], sw2[2048], sb2[64], snorm[INDIM];
  int t = threadIdx.x;
  for (int q = t; q < 320; q += 256) sw1[q] = w1g[q];
  for (int q = t; q < 2048; q += 256) sw2[q] = w2g[q];
  if (t < 32) sb1[t] = b1g[t];
  if (t < 64) sb2[t] = b2g[t];
  if (t < INDIM) snorm[t] = norm[t];
  __syncthreads();
  int node = blockIdx.x * 256 + t;  // < BATCH*N1
  float xv[INDIM];
#pragma unroll
  for (int d = 0; d < INDIM; ++d)
    xv[d] = x[(size_t)node * INDIM + d] * snorm[d];
  float t1[32];
#pragma unroll
  for (int c = 0; c < 32; ++c) {
    float acc = sb1[c];
#pragma unroll
    for (int d = 0; d < INDIM; ++d) acc += xv[d] * sw1[d * 32 + c];
    t1[c] = eluf(acc);
  }
  float* hr = g_h1 + (size_t)node * HID;
  float sq = 0.f;
  short s1l[HID], s2l[HID], s3l[HID];
#pragma unroll
  for (int c = 0; c < HID; ++c) {
    float acc = sb2[c];
#pragma unroll
    for (int d = 0; d < 32; ++d) acc += t1[d] * sw2[d * HID + c];
    float v = eluf(acc);
    hr[c] = v;
    sq += v * v;
    split3(v, s1l[c], s2l[c], s3l[c]);
  }
  store_frags(node, s1l, s2l, s3l);
  g_x2n[node] = sq;
}

// ---------------- MFMA Gram-matrix kNN (k=8), u32-key bubble selection -------
// D = H.H^T via mfma_f32_16x16x32_bf16 with 3-way bf16 split (12 MFMA per
// 16x16x64 tile; error ~2^-25). Selection: key32 = (encf(dd)&0xFFFFFF00)|ct
// (24-bit distance + 8-bit tile; lane's col c implicit, j = ct*16+c).
// UNCONDITIONAL 8-step v_min_u32/v_max_u32 bubble (16 inst/row) replaces
// r15's guarded u64 select-chain whose wave-divergent body (~64 inst, ~0.9
// any-lane probability) dominated VALU. Merge lifts to u64 (key32<<4)|c:
// equal-dd24 ordering = (ct,c) = lowest-j tie-break at 24-bit granularity.
template <int LEVEL>
__global__ __launch_bounds__(256, 1) void knn_kernel() {
  constexpr int n = LEVEL ? N2 : N1;
  __shared__ unsigned lm[4][16][16][KNN];  // 32 KB
  int b = blockIdx.x & 7;             // XCD-friendly batch swizzle
  int rb = (blockIdx.x >> 3) * 64;    // block row base
  int t = threadIdx.x;
  int wv = t >> 6, lane = t & 63;
  int q = lane >> 4, c = lane & 15;
  int rbase = rb + wv * 16;           // wave's 16-row strip
  const float* __restrict__ x2b = (LEVEL ? g_x2n2 : g_x2n) + (size_t)b * n;
  size_t abase = ((size_t)((b * n + rbase) >> 4)) * 1024 + lane * 8;
  short8 A1a = *(const short8*)(g_f1 + abase);
  short8 A1b = *(const short8*)(g_f1 + abase + 512);
  short8 A2a = *(const short8*)(g_f2 + abase);
  short8 A2b = *(const short8*)(g_f2 + abase + 512);
  short8 A3a = *(const short8*)(g_f3 + abase);
  short8 A3b = *(const short8*)(g_f3 + abase + 512);
  float x2r[4];
#pragma unroll
  for (int r = 0; r < 4; ++r) x2r[r] = x2b[rbase + q * 4 + r];
  unsigned best[4][KNN];
#pragma unroll
  for (int r = 0; r < 4; ++r)
#pragma unroll
    for (int p = 0; p < KNN; ++p) best[r][p] = 0xFFFFFFFFu;
  size_t bb = ((size_t)(b * n) >> 4) * 1024 + lane * 8;
  for (int ct = 0; ct < n / 16; ++ct, bb += 1024) {
    int cb = ct * 16 + c;  // this lane's column
    short8 B1a = *(const short8*)(g_f1 + bb);
    short8 B1b = *(const short8*)(g_f1 + bb + 512);
    short8 B2a = *(const short8*)(g_f2 + bb);
    short8 B2b = *(const short8*)(g_f2 + bb + 512);
    short8 B3a = *(const short8*)(g_f3 + bb);
    short8 B3b = *(const short8*)(g_f3 + bb + 512);
    f32x4 acc0 = {0.f, 0.f, 0.f, 0.f};
    f32x4 acc1 = {0.f, 0.f, 0.f, 0.f};
    acc0 = __builtin_amdgcn_mfma_f32_16x16x32_bf16(A1a, B1a, acc0, 0, 0, 0);
    acc1 = __builtin_amdgcn_mfma_f32_16x16x32_bf16(A1b, B1b, acc1, 0, 0, 0);
    acc0 = __builtin_amdgcn_mfma_f32_16x16x32_bf16(A1a, B2a, acc0, 0, 0, 0);
    acc1 = __builtin_amdgcn_mfma_f32_16x16x32_bf16(A1b, B2b, acc1, 0, 0, 0);
    acc0 = __builtin_amdgcn_mfma_f32_16x16x32_bf16(A2a, B1a, acc0, 0, 0, 0);
    acc1 = __builtin_amdgcn_mfma_f32_16x16x32_bf16(A2b, B1b, acc1, 0, 0, 0);
    acc0 = __builtin_amdgcn_mfma_f32_16x16x32_bf16(A1a, B3a, acc0, 0, 0, 0);
    acc1 = __builtin_amdgcn_mfma_f32_16x16x32_bf16(A1b, B3b, acc1, 0, 0, 0);
    acc0 = __builtin_amdgcn_mfma_f32_16x16x32_bf16(A2a, B2a, acc0, 0, 0, 0);
    acc1 = __builtin_amdgcn_mfma_f32_16x16x32_bf16(A2b, B2b, acc1, 0, 0, 0);
    acc0 = __builtin_amdgcn_mfma_f32_16x16x32_bf16(A3a, B1a, acc0, 0, 0, 0);
    acc1 = __builtin_amdgcn_mfma_f32_16x16x32_bf16(A3b, B1b, acc1, 0, 0, 0);
    float x2c = x2b[cb];
#pragma unroll
    for (int r = 0; r < 4; ++r) {
      int i = rbase + q * 4 + r;
      float dd = x2r[r] + x2c - 2.f * (acc0[r] + acc1[r]);
      unsigned ck = (encf(dd) & 0xFFFFFF00u) | (unsigned)ct;
      ck = (cb == i) ? 0xFFFFFFFFu : ck;
#pragma unroll
      for (int p = 0; p < KNN; ++p) {
        unsigned nb = min(best[r][p], ck);
        ck = max(best[r][p], ck);
        best[r][p] = nb;
      }
    }
  }
#pragma unroll
  for (int r = 0; r < 4; ++r)
#pragma unroll
    for (int p = 0; p < KNN; ++p) lm[wv][q * 4 + r][c][p] = best[r][p];
  __syncthreads();
  if (t < 64) {
    int wv2 = t >> 4, r16 = t & 15;
    u64 fin[KNN];
#pragma unroll
    for (int p = 0; p < KNN; ++p) fin[p] = ((u64)lm[wv2][r16][0][p]) << 4;
    for (int c2 = 1; c2 < 16; ++c2) {
#pragma unroll
      for (int p = 0; p < KNN; ++p) {
        u64 ck = (((u64)lm[wv2][r16][c2][p]) << 4) | (unsigned)c2;
        if (ck < fin[KNN - 1]) {
#pragma unroll
          for (int p2 = 0; p2 < KNN; ++p2) {
            u64 ob = fin[p2];
            bool ex = ob < ck;
            fin[p2] = ex ? ob : ck;
            ck = ex ? ck : ob;
          }
        }
      }
    }
    int row = rb + wv2 * 16 + r16;
    int* ob = g_nbr + ((size_t)b * n + row) * KNN;
#pragma unroll
    for (int p = 0; p < KNN; ++p) {
      int j = (int)((fin[p] >> 4) & 255u) * 16 + (int)(fin[p] & 15u);
      ob[p] = j & (n - 1);
    }
  }
}

// ---------------- per-node u/v for EdgeConv layer-1 factorization ------------
// [x_d, x_s-x_d]@W1+b1 = u_d + v_s with u = x@(Wtop-Wbot)+b1, v = x@Wbot.
// block = 64 nodes x 4 col-chunks (24 cols each; chunk == wave -> uniform).
__global__ __launch_bounds__(256) void uv_kernel(int level,
                                                 const float* __restrict__ w1g,
                                                 const float* __restrict__ b1g) {
  __shared__ float sw1[128 * 96];  // 48 KB
  __shared__ float sb1[96];
  int t = threadIdx.x;
  for (int q = t; q < 128 * 96; q += 256) sw1[q] = w1g[q];
  if (t < 96) sb1[t] = b1g[t];
  __syncthreads();
  const int n = level ? N2 : N1;
  const float* h = level ? g_h2 : g_h1;
  int b = blockIdx.x & 7;
  int nl = (blockIdx.x >> 3) * 64 + (t & 63);
  int c0 = (t >> 6) * 24;  // wave-uniform chunk
  size_t node = (size_t)b * n + nl;
  const float4* h4 = (const float4*)(h + node * HID);
  float hv[HID];
#pragma unroll
  for (int q = 0; q < 16; ++q) {
    float4 vv = h4[q];
    hv[4 * q] = vv.x; hv[4 * q + 1] = vv.y; hv[4 * q + 2] = vv.z; hv[4 * q + 3] = vv.w;
  }
  float ua[24], va[24];
#pragma unroll
  for (int c = 0; c < 24; ++c) { ua[c] = 0.f; va[c] = 0.f; }
  for (int d = 0; d < HID; ++d) {
    float hd = hv[d];
    const float* wt = sw1 + d * 96 + c0;        // wave-uniform -> broadcast
    const float* wb = sw1 + (HID + d) * 96 + c0;
#pragma unroll
    for (int c = 0; c < 24; ++c) {
      ua[c] += hd * wt[c];
      va[c] += hd * wb[c];
    }
  }
  float* ur = g_uu + node * 96 + c0;
  float* vr = g_vv + node * 96 + c0;
#pragma unroll
  for (int c = 0; c < 24; ++c) {
    ur[c] = ua[c] - va[c] + sb1[c0 + c];
    vr[c] = va[c];
  }
}

// ---------------- edge messages + max scatter (wave-per-node) ----------------
// Wave owns node i; lane = output channel. Per neighbor: stage tv[96] vectors
// in LDS (forward u_i+v_j, reverse u_j+v_i), then lane-parallel 96-step FMA.
// Forward messages max-reduce in a register (1 atomic run/node); reverse
// scatters to j, skipped when the edge is mutual (identical value produced by
// j's own forward pass). One scalar accumulator per lane -> no scratch spill.
__global__ __launch_bounds__(256) void edge_kernel(int level,
                                                   const float* __restrict__ w2g,
                                                   const float* __restrict__ b2g) {
  __shared__ __align__(16) float sw2[96 * 64];  // 24 KB, [kk][o]
  __shared__ float sb2[64];
  __shared__ __align__(16) float stA[4][96], stB[4][96];  // per-wave tv vectors
  int t = threadIdx.x;
  for (int q = t; q < 96 * 64; q += 256) sw2[q] = w2g[q];
  if (t < 64) sb2[t] = b2g[t];
  __syncthreads();
  const int n = level ? N2 : N1;
  unsigned* ekey = level ? g_ek2 : g_ek1;
  int b = blockIdx.x & 7;  // XCD swizzle
  int wv = t >> 6, lane = t & 63;
  int i = (blockIdx.x >> 3) * 4 + wv;  // wave-uniform node
  const int* nbb = g_nbr + (size_t)b * n * KNN;
  const float* ub = g_uu + (size_t)b * n * 96;
  const float* vb = g_vv + (size_t)b * n * 96;
  unsigned* eb = ekey + (size_t)b * n * HID;
  float ui0 = ub[(size_t)i * 96 + lane];
  float vi0 = vb[(size_t)i * 96 + lane];
  float ui1 = 0.f, vi1 = 0.f;
  if (lane < 32) {
    ui1 = ub[(size_t)i * 96 + 64 + lane];
    vi1 = vb[(size_t)i * 96 + 64 + lane];
  }
  const float biasv = sb2[lane];
  float macc = -1.0f;
  for (int k = 0; k < KNN; ++k) {
    __syncthreads();  // protect prev iteration's tv reads before overwrite
    int j = nbb[(size_t)i * KNN + k] & (n - 1);  // wave-uniform
    bool needB = true;
#pragma unroll
    for (int k2 = 0; k2 < KNN; ++k2)
      needB = needB && ((nbb[(size_t)j * KNN + k2] & (n - 1)) != i);
    {
      float vj0 = vb[(size_t)j * 96 + lane];
      float uj0 = ub[(size_t)j * 96 + lane];
      stA[wv][lane] = eluf(ui0 + vj0);
      if (needB) stB[wv][lane] = eluf(uj0 + vi0);
      if (lane < 32) {
        float vj1 = vb[(size_t)j * 96 + 64 + lane];
        float uj1 = ub[(size_t)j * 96 + 64 + lane];
        stA[wv][64 + lane] = eluf(ui1 + vj1);
        if (needB) stB[wv][64 + lane] = eluf(uj1 + vi1);
      }
    }
    __syncthreads();  // make tv visible across lanes
    float a0 = 0.f, a1 = 0.f, b0 = 0.f, b1 = 0.f;
    if (needB) {
      for (int kk = 0; kk < 96; kk += 4) {
        float4 ta = *(const float4*)&stA[wv][kk];
        float4 tb = *(const float4*)&stB[wv][kk];
        float w0 = sw2[(kk + 0) * 64 + lane];
        float w1 = sw2[(kk + 1) * 64 + lane];
        float w2v = sw2[(kk + 2) * 64 + lane];
        float w3 = sw2[(kk + 3) * 64 + lane];
        a0 += ta.x * w0 + ta.y * w1;
        a1 += ta.z * w2v + ta.w * w3;
        b0 += tb.x * w0 + tb.y * w1;
        b1 += tb.z * w2v + tb.w * w3;
      }
      atomicMax(&eb[(size_t)j * HID + lane],
                enc_safe(eluf(biasv + b0 + b1)));
    } else {
      for (int kk = 0; kk < 96; kk += 4) {
        float4 ta = *(const float4*)&stA[wv][kk];
        float w0 = sw2[(kk + 0) * 64 + lane];
        float w1 = sw2[(kk + 1) * 64 + lane];
        float w2v = sw2[(kk + 2) * 64 + lane];
        float w3 = sw2[(kk + 3) * 64 + lane];
        a0 += ta.x * w0 + ta.y * w1;
        a1 += ta.z * w2v + ta.w * w3;
      }
    }
    macc = fmaxf(macc, eluf(biasv + a0 + a1));
  }
  atomicMax(&eb[(size_t)i * HID + lane], enc_safe(macc));
}

// ---------------- pairwise max pool + norms + bf16 splits --------------------
__global__ __launch_bounds__(256) void pool_kernel() {
  int node = blockIdx.x * 256 + threadIdx.x;  // < BATCH*N2
  int b = node >> 11;
  int m = node & (N2 - 1);
  const unsigned* e = g_ek1 + ((size_t)b * N1 + 2 * m) * HID;
  float* hr = g_h2 + (size_t)node * HID;
  float sq = 0.f;
  short s1l[HID], s2l[HID], s3l[HID];
#pragma unroll
  for (int d = 0; d < HID; ++d) {
    float mx = fmaxf(dec_safe(e[d]), dec_safe(e[HID + d]));
    hr[d] = mx;
    sq += mx * mx;
    split3(mx, s1l[d], s2l[d], s3l[d]);
  }
  store_frags(node, s1l, s2l, s3l);
  g_x2n2[node] = sq;
}

// ---------------- global max + output MLP -> FLOAT32 output ------------------
__global__ __launch_bounds__(64) void final_kernel(
    const float* __restrict__ wo1, const float* __restrict__ bo1,
    const float* __restrict__ wo2, const float* __restrict__ bo2,
    const float* __restrict__ wo3, const float* __restrict__ bo3,
    float* __restrict__ out) {
  __shared__ float g[HID];
  __shared__ float o1s[HID];
  __shared__ float o2s[32];
  int b = blockIdx.x;
  int t = threadIdx.x;  // 0..63
  const unsigned* e = g_ek2 + (size_t)b * N2 * HID;
  unsigned mk = 0u;
  for (int m = 0; m < N2; ++m) {
    unsigned q = e[(size_t)m * HID + t];
    mk = q > mk ? q : mk;
  }
  g[t] = dec_safe(mk);
  __syncthreads();
  {
    float a1 = bo1[t];
    for (int d = 0; d < HID; ++d) a1 += g[d] * wo1[d * HID + t];
    o1s[t] = eluf(a1);
  }
  __syncthreads();
  if (t < 32) {
    float a2 = bo2[t];
    for (int d = 0; d < HID; ++d) a2 += o1s[d] * wo2[d * 32 + t];
    o2s[t] = eluf(a2);
  }
  __syncthreads();
  if (t == 0) {
    float acc0 = bo3[0];
    float acc1 = bo3[1];
    for (int d = 0; d < 32; ++d) {
      acc0 += o2s[d] * wo3[d * 2 + 0];
      acc1 += o2s[d] * wo3[d * 2 + 1];
    }
    float met = fmaxf(acc0, 0.f) + log1pf(expf(-fabsf(acc0)));      // softplus
    float phi = 3.14159265358979f * (2.f / (1.f + expf(-acc1)) - 1.f);
    out[b * 2 + 0] = met;
    out[b * 2 + 1] = phi;
  }
}

extern "C" void kernel_launch(void* const* d_in, const int* in_sizes, int n_in,
                              void* d_out, int out_size, void* d_ws,
                              size_t ws_size, hipStream_t stream) {
  const float* x     = (const float*)d_in[0];
  const float* dnorm = (const float*)d_in[1];
  const float* w_in1 = (const float*)d_in[2];
  const float* b_in1 = (const float*)d_in[3];
  const float* w_in2 = (const float*)d_in[4];
  const float* b_in2 = (const float*)d_in[5];
  const float* w_c1a = (const float*)d_in[6];
  const float* b_c1a = (const float*)d_in[7];
  const float* w_c1b = (const float*)d_in[8];
  const float* b_c1b = (const float*)d_in[9];
  const float* w_c2a = (const float*)d_in[10];
  const float* b_c2a = (const float*)d_in[11];
  const float* w_c2b = (const float*)d_in[12];
  const float* b_c2b = (const float*)d_in[13];
  const float* w_o1  = (const float*)d_in[14];
  const float* b_o1  = (const float*)d_in[15];
  const float* w_o2  = (const float*)d_in[16];
  const float* b_o2  = (const float*)d_in[17];
  const float* w_o3  = (const float*)d_in[18];
  const float* b_o3  = (const float*)d_in[19];

  init_kernel<<<(BATCH * N1 * HID + BATCH * N2 * HID) / 4 / 256, 256, 0,
                stream>>>();
  input_mlp<<<BATCH * N1 / 256, 256, 0, stream>>>(x, dnorm, w_in1, b_in1,
                                                  w_in2, b_in2);
  knn_kernel<0><<<8 * (N1 / 64), 256, 0, stream>>>();
  uv_kernel<<<8 * (N1 / 64), 256, 0, stream>>>(0, w_c1a, b_c1a);
  edge_kernel<<<8 * (N1 / 4), 256, 0, stream>>>(0, w_c1b, b_c1b);
  pool_kernel<<<BATCH * N2 / 256, 256, 0, stream>>>();
  knn_kernel<1><<<8 * (N2 / 64), 256, 0, stream>>>();
  uv_kernel<<<8 * (N2 / 64), 256, 0, stream>>>(1, w_c2a, b_c2a);
  edge_kernel<<<8 * (N2 / 4), 256, 0, stream>>>(1, w_c2b, b_c2b);
  final_kernel<<<BATCH, 64, 0, stream>>>(w_o1, b_o1, w_o2, b_o2, w_o3, b_o3,
                                         (float*)d_out);
}

// Round 17
// 640.774 us; speedup vs baseline: 2.0613x; 1.3739x over previous
//
#include <hip/hip_runtime.h>
#include <hip/hip_bf16.h>

#define BATCH 8
#define N1 4096
#define N2 2048
#define HID 64
#define KNN 8
#define INDIM 10

using u64 = unsigned long long;
using bf16 = __hip_bfloat16;
typedef __attribute__((ext_vector_type(8))) short short8;
typedef __attribute__((ext_vector_type(4))) float f32x4;

// Scratch in static device memory (~110 MB): d_ws size is not guaranteed.
// Every buffer is fully rewritten each call (or re-initialized by init_kernel).
__device__ __align__(256) float    g_h1[BATCH * N1 * HID];
__device__ __align__(256) float    g_h2[BATCH * N2 * HID];
__device__ __align__(256) float    g_x2n[BATCH * N1];
__device__ __align__(256) float    g_x2n2[BATCH * N2];
__device__ __align__(256) int      g_nbr[BATCH * N1 * KNN];
__device__ __align__(256) float    g_uu[BATCH * N1 * 96];
__device__ __align__(256) float    g_vv[BATCH * N1 * 96];
__device__ __align__(256) unsigned g_ek1[BATCH * N1 * HID];
__device__ __align__(256) unsigned g_ek2[BATCH * N2 * HID];
// 3-way bf16 split of h in MFMA FRAGMENT-MAJOR layout (kNN):
// [tile16][chunk(2)][q(4)][c(16)][j(8)] shorts; node i=tile*16+c.
__device__ __align__(256) short    g_f1[BATCH * N1 * HID];
__device__ __align__(256) short    g_f2[BATCH * N1 * HID];
__device__ __align__(256) short    g_f3[BATCH * N1 * HID];
// frag-major f32 copies of u,v for edge MFMA A-prep (coalesced self-row
// loads): [tile16][kc(3)][q(4)][c(16)][j(8)] floats, node = tile*16+c,
// hidden dim kk = kc*32+q*8+j.
__device__ __align__(256) float    g_uf[BATCH * N1 * 96];
__device__ __align__(256) float    g_vf[BATCH * N1 * 96];
// 2-way bf16 split W2 fragments: [level][no(4)][kc(3)][lane(64)][j(8)]
__device__ __align__(256) short    g_wf1[2 * 4 * 3 * 64 * 8];
__device__ __align__(256) short    g_wf2[2 * 4 * 3 * 64 * 8];

__device__ __forceinline__ float eluf(float x) { return x > 0.f ? x : __expf(x) - 1.f; }
// order-isomorphic float->u32 encoding: a<b  <=>  enc(a)<enc(b) (unsigned)
__device__ __forceinline__ unsigned encf(float f) {
  unsigned u = __float_as_uint(f);
  return (u & 0x80000000u) ? ~u : (u | 0x80000000u);
}
__device__ __forceinline__ float decf(unsigned k) {
  unsigned u = (k & 0x80000000u) ? (k & 0x7FFFFFFFu) : ~k;
  return __uint_as_float(u);
}
// encf(-1.0f): ELU outputs are strictly > -1 => legal max-identity.
#define ENC_NEG1 0x407FFFFFu
__device__ __forceinline__ unsigned enc_safe(float v) {
  if (!(v == v)) return ENC_NEG1;
  return encf(v);
}
__device__ __forceinline__ float dec_safe(unsigned k) {
  float v = decf(k);
  if (!(v == v)) return -1.0f;
  return fminf(fmaxf(v, -3.0e38f), 3.0e38f);
}
// 3-way bf16 split: v ~= b1 + b2 + b3 (error ~2^-25 relative)
__device__ __forceinline__ void split3(float v, short& b1, short& b2, short& b3) {
  bf16 x1 = __float2bfloat16(v);
  float r1 = v - __bfloat162float(x1);
  bf16 x2 = __float2bfloat16(r1);
  float r2 = r1 - __bfloat162float(x2);
  bf16 x3 = __float2bfloat16(r2);
  b1 = *(short*)&x1; b2 = *(short*)&x2; b3 = *(short*)&x3;
}
// 2-way bf16 split
__device__ __forceinline__ void split2(float v, short& b1, short& b2) {
  bf16 x1 = __float2bfloat16(v);
  float r1 = v - __bfloat162float(x1);
  bf16 x2 = __float2bfloat16(r1);
  b1 = *(short*)&x1; b2 = *(short*)&x2;
}
// write one node's 64 splits into kNN fragment-major layout
__device__ __forceinline__ void store_frags(int node, const short* s1,
                                            const short* s2, const short* s3) {
  size_t tb = ((size_t)(node >> 4)) * 1024 + (node & 15) * 8;
#pragma unroll
  for (int chunk = 0; chunk < 2; ++chunk) {
#pragma unroll
    for (int q = 0; q < 4; ++q) {
      size_t a = tb + chunk * 512 + q * 128;
      int k = chunk * 32 + q * 8;
      *(short8*)(g_f1 + a) = *(const short8*)(s1 + k);
      *(short8*)(g_f2 + a) = *(const short8*)(s2 + k);
      *(short8*)(g_f3 + a) = *(const short8*)(s3 + k);
    }
  }
}
// elu(a+b) for 8 floats -> 2-way split short8 frags
__device__ __forceinline__ void tv_frag(float4 a0, float4 a1, float4 b0,
                                        float4 b1, short8& s1, short8& s2) {
  float v[8] = {a0.x + b0.x, a0.y + b0.y, a0.z + b0.z, a0.w + b0.w,
                a1.x + b1.x, a1.y + b1.y, a1.z + b1.z, a1.w + b1.w};
#pragma unroll
  for (int e = 0; e < 8; ++e) {
    float t = eluf(v[e]);
    short p1, p2;
    split2(t, p1, p2);
    s1[e] = p1; s2[e] = p2;
  }
}

// ---------------- init the scatter-max accumulators --------------------------
__global__ __launch_bounds__(256) void init_kernel() {
  int t = blockIdx.x * 256 + threadIdx.x;
  uint4 z = make_uint4(ENC_NEG1, ENC_NEG1, ENC_NEG1, ENC_NEG1);
  const int n1 = BATCH * N1 * HID / 4;
  if (t < n1) ((uint4*)g_ek1)[t] = z;
  else ((uint4*)g_ek2)[t - n1] = z;
}

// ---------------- W2 -> 2-way-split MFMA B-fragments (once per launch) -------
// B-frag element: B[k=kc*32+(lane>>4)*8+j][n=no*16+(lane&15)] = W2[k][n]
__global__ __launch_bounds__(256) void wfrag_kernel(const float* __restrict__ w1,
                                                    const float* __restrict__ w2) {
  int level = blockIdx.x;
  const float* w = level ? w2 : w1;
  for (int idx = threadIdx.x; idx < 6144; idx += 256) {
    int no = idx / 1536;
    int rem = idx - no * 1536;
    int kc = rem / 512;
    int rem2 = rem - kc * 512;
    int lane = rem2 >> 3;
    int j = rem2 & 7;
    int k = kc * 32 + (lane >> 4) * 8 + j;
    int o = no * 16 + (lane & 15);
    short b1, b2;
    split2(w[k * 64 + o], b1, b2);
    g_wf1[level * 6144 + idx] = b1;
    g_wf2[level * 6144 + idx] = b2;
  }
}

// ---------------- input MLP: x*norm -> 32 (elu) -> 64 (elu) + |h|^2 + splits -
__global__ __launch_bounds__(256) void input_mlp(
    const float* __restrict__ x, const float* __restrict__ norm,
    const float* __restrict__ w1g, const float* __restrict__ b1g,
    const float* __restrict__ w2g, const float* __restrict__ b2g) {
  __shared__ float sw1[320], sb1[32], sw2[2048], sb2[64], snorm[INDIM];
  int t = threadIdx.x;
  for (int q = t; q < 320; q += 256) sw1[q] = w1g[q];
  for (int q = t; q < 2048; q += 256) sw2[q] = w2g[q];
  if (t < 32) sb1[t] = b1g[t];
  if (t < 64) sb2[t] = b2g[t];
  if (t < INDIM) snorm[t] = norm[t];
  __syncthreads();
  int node = blockIdx.x * 256 + t;  // < BATCH*N1
  float xv[INDIM];
#pragma unroll
  for (int d = 0; d < INDIM; ++d)
    xv[d] = x[(size_t)node * INDIM + d] * snorm[d];
  float t1[32];
#pragma unroll
  for (int c = 0; c < 32; ++c) {
    float acc = sb1[c];
#pragma unroll
    for (int d = 0; d < INDIM; ++d) acc += xv[d] * sw1[d * 32 + c];
    t1[c] = eluf(acc);
  }
  float* hr = g_h1 + (size_t)node * HID;
  float sq = 0.f;
  short s1l[HID], s2l[HID], s3l[HID];
#pragma unroll
  for (int c = 0; c < HID; ++c) {
    float acc = sb2[c];
#pragma unroll
    for (int d = 0; d < 32; ++d) acc += t1[d] * sw2[d * HID + c];
    float v = eluf(acc);
    hr[c] = v;
    sq += v * v;
    split3(v, s1l[c], s2l[c], s3l[c]);
  }
  store_frags(node, s1l, s2l, s3l);
  g_x2n[node] = sq;
}

// ---------------- MFMA Gram-matrix kNN (k=8), u32-key bubble selection -------
template <int LEVEL>
__global__ __launch_bounds__(256, 1) void knn_kernel() {
  constexpr int n = LEVEL ? N2 : N1;
  __shared__ unsigned lm[4][16][16][KNN];  // 32 KB
  int b = blockIdx.x & 7;             // XCD-friendly batch swizzle
  int rb = (blockIdx.x >> 3) * 64;    // block row base
  int t = threadIdx.x;
  int wv = t >> 6, lane = t & 63;
  int q = lane >> 4, c = lane & 15;
  int rbase = rb + wv * 16;           // wave's 16-row strip
  const float* __restrict__ x2b = (LEVEL ? g_x2n2 : g_x2n) + (size_t)b * n;
  size_t abase = ((size_t)((b * n + rbase) >> 4)) * 1024 + lane * 8;
  short8 A1a = *(const short8*)(g_f1 + abase);
  short8 A1b = *(const short8*)(g_f1 + abase + 512);
  short8 A2a = *(const short8*)(g_f2 + abase);
  short8 A2b = *(const short8*)(g_f2 + abase + 512);
  short8 A3a = *(const short8*)(g_f3 + abase);
  short8 A3b = *(const short8*)(g_f3 + abase + 512);
  float x2r[4];
#pragma unroll
  for (int r = 0; r < 4; ++r) x2r[r] = x2b[rbase + q * 4 + r];
  unsigned best[4][KNN];
#pragma unroll
  for (int r = 0; r < 4; ++r)
#pragma unroll
    for (int p = 0; p < KNN; ++p) best[r][p] = 0xFFFFFFFFu;
  size_t bb = ((size_t)(b * n) >> 4) * 1024 + lane * 8;
  for (int ct = 0; ct < n / 16; ++ct, bb += 1024) {
    int cb = ct * 16 + c;  // this lane's column
    short8 B1a = *(const short8*)(g_f1 + bb);
    short8 B1b = *(const short8*)(g_f1 + bb + 512);
    short8 B2a = *(const short8*)(g_f2 + bb);
    short8 B2b = *(const short8*)(g_f2 + bb + 512);
    short8 B3a = *(const short8*)(g_f3 + bb);
    short8 B3b = *(const short8*)(g_f3 + bb + 512);
    f32x4 acc0 = {0.f, 0.f, 0.f, 0.f};
    f32x4 acc1 = {0.f, 0.f, 0.f, 0.f};
    acc0 = __builtin_amdgcn_mfma_f32_16x16x32_bf16(A1a, B1a, acc0, 0, 0, 0);
    acc1 = __builtin_amdgcn_mfma_f32_16x16x32_bf16(A1b, B1b, acc1, 0, 0, 0);
    acc0 = __builtin_amdgcn_mfma_f32_16x16x32_bf16(A1a, B2a, acc0, 0, 0, 0);
    acc1 = __builtin_amdgcn_mfma_f32_16x16x32_bf16(A1b, B2b, acc1, 0, 0, 0);
    acc0 = __builtin_amdgcn_mfma_f32_16x16x32_bf16(A2a, B1a, acc0, 0, 0, 0);
    acc1 = __builtin_amdgcn_mfma_f32_16x16x32_bf16(A2b, B1b, acc1, 0, 0, 0);
    acc0 = __builtin_amdgcn_mfma_f32_16x16x32_bf16(A1a, B3a, acc0, 0, 0, 0);
    acc1 = __builtin_amdgcn_mfma_f32_16x16x32_bf16(A1b, B3b, acc1, 0, 0, 0);
    acc0 = __builtin_amdgcn_mfma_f32_16x16x32_bf16(A2a, B2a, acc0, 0, 0, 0);
    acc1 = __builtin_amdgcn_mfma_f32_16x16x32_bf16(A2b, B2b, acc1, 0, 0, 0);
    acc0 = __builtin_amdgcn_mfma_f32_16x16x32_bf16(A3a, B1a, acc0, 0, 0, 0);
    acc1 = __builtin_amdgcn_mfma_f32_16x16x32_bf16(A3b, B1b, acc1, 0, 0, 0);
    float x2c = x2b[cb];
#pragma unroll
    for (int r = 0; r < 4; ++r) {
      int i = rbase + q * 4 + r;
      float dd = x2r[r] + x2c - 2.f * (acc0[r] + acc1[r]);
      unsigned ck = (encf(dd) & 0xFFFFFF00u) | (unsigned)ct;
      ck = (cb == i) ? 0xFFFFFFFFu : ck;
#pragma unroll
      for (int p = 0; p < KNN; ++p) {
        unsigned nb = min(best[r][p], ck);
        ck = max(best[r][p], ck);
        best[r][p] = nb;
      }
    }
  }
#pragma unroll
  for (int r = 0; r < 4; ++r)
#pragma unroll
    for (int p = 0; p < KNN; ++p) lm[wv][q * 4 + r][c][p] = best[r][p];
  __syncthreads();
  if (t < 64) {
    int wv2 = t >> 4, r16 = t & 15;
    u64 fin[KNN];
#pragma unroll
    for (int p = 0; p < KNN; ++p) fin[p] = ((u64)lm[wv2][r16][0][p]) << 4;
    for (int c2 = 1; c2 < 16; ++c2) {
#pragma unroll
      for (int p = 0; p < KNN; ++p) {
        u64 ck = (((u64)lm[wv2][r16][c2][p]) << 4) | (unsigned)c2;
        if (ck < fin[KNN - 1]) {
#pragma unroll
          for (int p2 = 0; p2 < KNN; ++p2) {
            u64 ob = fin[p2];
            bool ex = ob < ck;
            fin[p2] = ex ? ob : ck;
            ck = ex ? ck : ob;
          }
        }
      }
    }
    int row = rb + wv2 * 16 + r16;
    int* ob = g_nbr + ((size_t)b * n + row) * KNN;
#pragma unroll
    for (int p = 0; p < KNN; ++p) {
      int j = (int)((fin[p] >> 4) & 255u) * 16 + (int)(fin[p] & 15u);
      ob[p] = j & (n - 1);
    }
  }
}

// ---------------- per-node u/v for EdgeConv layer-1 factorization ------------
// Also writes frag-major f32 copies g_uf/g_vf for the MFMA edge kernel.
__global__ __launch_bounds__(256) void uv_kernel(int level,
                                                 const float* __restrict__ w1g,
                                                 const float* __restrict__ b1g) {
  __shared__ float sw1[128 * 96];  // 48 KB
  __shared__ float sb1[96];
  int t = threadIdx.x;
  for (int q = t; q < 128 * 96; q += 256) sw1[q] = w1g[q];
  if (t < 96) sb1[t] = b1g[t];
  __syncthreads();
  const int n = level ? N2 : N1;
  const float* h = level ? g_h2 : g_h1;
  int b = blockIdx.x & 7;
  int nl = (blockIdx.x >> 3) * 64 + (t & 63);
  int c0 = (t >> 6) * 24;  // wave-uniform chunk
  size_t node = (size_t)b * n + nl;
  const float4* h4 = (const float4*)(h + node * HID);
  float hv[HID];
#pragma unroll
  for (int q = 0; q < 16; ++q) {
    float4 vv = h4[q];
    hv[4 * q] = vv.x; hv[4 * q + 1] = vv.y; hv[4 * q + 2] = vv.z; hv[4 * q + 3] = vv.w;
  }
  float ua[24], va[24];
#pragma unroll
  for (int c = 0; c < 24; ++c) { ua[c] = 0.f; va[c] = 0.f; }
  for (int d = 0; d < HID; ++d) {
    float hd = hv[d];
    const float* wt = sw1 + d * 96 + c0;        // wave-uniform -> broadcast
    const float* wb = sw1 + (HID + d) * 96 + c0;
#pragma unroll
    for (int c = 0; c < 24; ++c) {
      ua[c] += hd * wt[c];
      va[c] += hd * wb[c];
    }
  }
  float* ur = g_uu + node * 96 + c0;
  float* vr = g_vv + node * 96 + c0;
  size_t ftb = (node >> 4) * 96 + (nl & 15) * 8;  // frag-major base (floats)
#pragma unroll
  for (int c = 0; c < 24; ++c) {
    float uval = ua[c] - va[c] + sb1[c0 + c];
    float vval = va[c];
    ur[c] = uval;
    vr[c] = vval;
    int kk = c0 + c;
    size_t fa = ftb * 1 + (size_t)((kk >> 5) * 512 + ((kk >> 3) & 3) * 128) +
                ((node >> 4) * 1536 - (node >> 4) * 96) + (kk & 7);
    // simplified: fa = (node>>4)*1536 + (kk>>5)*512 + ((kk>>3)&3)*128 + (nl&15)*8 + (kk&7)
    fa = (node >> 4) * 1536 + (size_t)((kk >> 5) * 512 + ((kk >> 3) & 3) * 128 +
                                       (nl & 15) * 8 + (kk & 7));
    g_uf[fa] = uval;
    g_vf[fa] = vval;
  }
}

// ---------------- MFMA edge messages + max scatter ---------------------------
// Wave = 16 nodes (one frag tile). Per neighbor slot: A-frags of
// tv=elu(u_i+v_j) (fwd) and elu(u_j+v_i) (rev) built in registers (self rows
// from frag-major g_uf/g_vf coalesced, neighbor rows via float4 gathers),
// 2-way bf16 split x 2-way split W (3 cross terms) -> 72 MFMAs/slot. C/D:
// row=q*4+r=message(node), col=c=channel-within-tile. Fwd max-reduced over
// slots in registers (1 atomic run/node); rev scattered every slot
// (duplicates idempotent under max). No LDS at all.
template <int LEVEL>
__global__ __launch_bounds__(256, 1) void edge_kernel(
    const float* __restrict__ b2g) {
  constexpr int n = LEVEL ? N2 : N1;
  unsigned* ekey = LEVEL ? g_ek2 : g_ek1;
  int b = blockIdx.x & 7;  // XCD swizzle
  int t = threadIdx.x;
  int wv = t >> 6, lane = t & 63;
  int q = lane >> 4, c = lane & 15;
  int base16 = (blockIdx.x >> 3) * 64 + wv * 16;
  int node_c = base16 + c;
  const int* nbb = g_nbr + (size_t)b * n * KNN;
  const float* ub = g_uu + (size_t)b * n * 96;
  const float* vb = g_vv + (size_t)b * n * 96;
  size_t ftile = ((size_t)(b * n + base16) >> 4) * 1536;
  unsigned* eb = ekey + (size_t)b * n * HID;
  // hoisted W fragments: [no][kc], 2 splits
  short8 W1f[4][3], W2f[4][3];
#pragma unroll
  for (int no = 0; no < 4; ++no)
#pragma unroll
    for (int kc = 0; kc < 3; ++kc) {
      int off = LEVEL * 6144 + ((no * 3 + kc) * 64 + lane) * 8;
      W1f[no][kc] = *(const short8*)(g_wf1 + off);
      W2f[no][kc] = *(const short8*)(g_wf2 + off);
    }
  float biasv[4];
#pragma unroll
  for (int no = 0; no < 4; ++no) biasv[no] = b2g[no * 16 + c];
  float macc[16];
#pragma unroll
  for (int e = 0; e < 16; ++e) macc[e] = -1.0f;
  for (int slot = 0; slot < KNN; ++slot) {
    int jn = nbb[(size_t)node_c * KNN + slot] & (n - 1);
    short8 t1[3], t2[3], r1[3], r2[3];
#pragma unroll
    for (int kc = 0; kc < 3; ++kc) {
      size_t fo = ftile + kc * 512 + lane * 8;
      float4 su0 = *(const float4*)(g_uf + fo);
      float4 su1 = *(const float4*)(g_uf + fo + 4);
      float4 sv0 = *(const float4*)(g_vf + fo);
      float4 sv1 = *(const float4*)(g_vf + fo + 4);
      size_t go = (size_t)jn * 96 + kc * 32 + q * 8;
      float4 gv0 = *(const float4*)(vb + go);
      float4 gv1 = *(const float4*)(vb + go + 4);
      float4 gu0 = *(const float4*)(ub + go);
      float4 gu1 = *(const float4*)(ub + go + 4);
      tv_frag(su0, su1, gv0, gv1, t1[kc], t2[kc]);   // fwd: u_i + v_j
      tv_frag(gu0, gu1, sv0, sv1, r1[kc], r2[kc]);   // rev: u_j + v_i
    }
    f32x4 aF[4], aR[4];
#pragma unroll
    for (int no = 0; no < 4; ++no) {
      aF[no] = (f32x4){0.f, 0.f, 0.f, 0.f};
      aR[no] = (f32x4){0.f, 0.f, 0.f, 0.f};
    }
#pragma unroll
    for (int no = 0; no < 4; ++no)
#pragma unroll
      for (int kc = 0; kc < 3; ++kc) {
        aF[no] = __builtin_amdgcn_mfma_f32_16x16x32_bf16(t1[kc], W1f[no][kc], aF[no], 0, 0, 0);
        aF[no] = __builtin_amdgcn_mfma_f32_16x16x32_bf16(t2[kc], W1f[no][kc], aF[no], 0, 0, 0);
        aF[no] = __builtin_amdgcn_mfma_f32_16x16x32_bf16(t1[kc], W2f[no][kc], aF[no], 0, 0, 0);
        aR[no] = __builtin_amdgcn_mfma_f32_16x16x32_bf16(r1[kc], W1f[no][kc], aR[no], 0, 0, 0);
        aR[no] = __builtin_amdgcn_mfma_f32_16x16x32_bf16(r2[kc], W1f[no][kc], aR[no], 0, 0, 0);
        aR[no] = __builtin_amdgcn_mfma_f32_16x16x32_bf16(r1[kc], W2f[no][kc], aR[no], 0, 0, 0);
      }
    // rev scatter: row r's message goes to its neighbor j_row
#pragma unroll
    for (int r = 0; r < 4; ++r) {
      int jr = nbb[(size_t)(base16 + q * 4 + r) * KNN + slot] & (n - 1);
#pragma unroll
      for (int no = 0; no < 4; ++no) {
        float mv = eluf(aR[no][r] + biasv[no]);
        atomicMax(&eb[(size_t)jr * HID + no * 16 + c], enc_safe(mv));
      }
    }
    // fwd: max-accumulate
#pragma unroll
    for (int no = 0; no < 4; ++no)
#pragma unroll
      for (int r = 0; r < 4; ++r)
        macc[no * 4 + r] = fmaxf(macc[no * 4 + r], eluf(aF[no][r] + biasv[no]));
  }
#pragma unroll
  for (int r = 0; r < 4; ++r) {
    size_t ib = (size_t)(base16 + q * 4 + r) * HID;
#pragma unroll
    for (int no = 0; no < 4; ++no)
      atomicMax(&eb[ib + no * 16 + c], enc_safe(macc[no * 4 + r]));
  }
}

// ---------------- pairwise max pool + norms + bf16 splits --------------------
__global__ __launch_bounds__(256) void pool_kernel() {
  int node = blockIdx.x * 256 + threadIdx.x;  // < BATCH*N2
  int b = node >> 11;
  int m = node & (N2 - 1);
  const unsigned* e = g_ek1 + ((size_t)b * N1 + 2 * m) * HID;
  float* hr = g_h2 + (size_t)node * HID;
  float sq = 0.f;
  short s1l[HID], s2l[HID], s3l[HID];
#pragma unroll
  for (int d = 0; d < HID; ++d) {
    float mx = fmaxf(dec_safe(e[d]), dec_safe(e[HID + d]));
    hr[d] = mx;
    sq += mx * mx;
    split3(mx, s1l[d], s2l[d], s3l[d]);
  }
  store_frags(node, s1l, s2l, s3l);
  g_x2n2[node] = sq;
}

// ---------------- global max + output MLP -> FLOAT32 output ------------------
__global__ __launch_bounds__(64) void final_kernel(
    const float* __restrict__ wo1, const float* __restrict__ bo1,
    const float* __restrict__ wo2, const float* __restrict__ bo2,
    const float* __restrict__ wo3, const float* __restrict__ bo3,
    float* __restrict__ out) {
  __shared__ float g[HID];
  __shared__ float o1s[HID];
  __shared__ float o2s[32];
  int b = blockIdx.x;
  int t = threadIdx.x;  // 0..63
  const unsigned* e = g_ek2 + (size_t)b * N2 * HID;
  unsigned mk = 0u;
  for (int m = 0; m < N2; ++m) {
    unsigned q = e[(size_t)m * HID + t];
    mk = q > mk ? q : mk;
  }
  g[t] = dec_safe(mk);
  __syncthreads();
  {
    float a1 = bo1[t];
    for (int d = 0; d < HID; ++d) a1 += g[d] * wo1[d * HID + t];
    o1s[t] = eluf(a1);
  }
  __syncthreads();
  if (t < 32) {
    float a2 = bo2[t];
    for (int d = 0; d < HID; ++d) a2 += o1s[d] * wo2[d * 32 + t];
    o2s[t] = eluf(a2);
  }
  __syncthreads();
  if (t == 0) {
    float acc0 = bo3[0];
    float acc1 = bo3[1];
    for (int d = 0; d < 32; ++d) {
      acc0 += o2s[d] * wo3[d * 2 + 0];
      acc1 += o2s[d] * wo3[d * 2 + 1];
    }
    float met = fmaxf(acc0, 0.f) + log1pf(expf(-fabsf(acc0)));      // softplus
    float phi = 3.14159265358979f * (2.f / (1.f + expf(-acc1)) - 1.f);
    out[b * 2 + 0] = met;
    out[b * 2 + 1] = phi;
  }
}

extern "C" void kernel_launch(void* const* d_in, const int* in_sizes, int n_in,
                              void* d_out, int out_size, void* d_ws,
                              size_t ws_size, hipStream_t stream) {
  const float* x     = (const float*)d_in[0];
  const float* dnorm = (const float*)d_in[1];
  const float* w_in1 = (const float*)d_in[2];
  const float* b_in1 = (const float*)d_in[3];
  const float* w_in2 = (const float*)d_in[4];
  const float* b_in2 = (const float*)d_in[5];
  const float* w_c1a = (const float*)d_in[6];
  const float* b_c1a = (const float*)d_in[7];
  const float* w_c1b = (const float*)d_in[8];
  const float* b_c1b = (const float*)d_in[9];
  const float* w_c2a = (const float*)d_in[10];
  const float* b_c2a = (const float*)d_in[11];
  const float* w_c2b = (const float*)d_in[12];
  const float* b_c2b = (const float*)d_in[13];
  const float* w_o1  = (const float*)d_in[14];
  const float* b_o1  = (const float*)d_in[15];
  const float* w_o2  = (const float*)d_in[16];
  const float* b_o2  = (const float*)d_in[17];
  const float* w_o3  = (const float*)d_in[18];
  const float* b_o3  = (const float*)d_in[19];

  init_kernel<<<(BATCH * N1 * HID + BATCH * N2 * HID) / 4 / 256, 256, 0,
                stream>>>();
  wfrag_kernel<<<2, 256, 0, stream>>>(w_c1b, w_c2b);
  input_mlp<<<BATCH * N1 / 256, 256, 0, stream>>>(x, dnorm, w_in1, b_in1,
                                                  w_in2, b_in2);
  knn_kernel<0><<<8 * (N1 / 64), 256, 0, stream>>>();
  uv_kernel<<<8 * (N1 / 64), 256, 0, stream>>>(0, w_c1a, b_c1a);
  edge_kernel<0><<<8 * (N1 / 64), 256, 0, stream>>>(b_c1b);
  pool_kernel<<<BATCH * N2 / 256, 256, 0, stream>>>();
  knn_kernel<1><<<8 * (N2 / 64), 256, 0, stream>>>();
  uv_kernel<<<8 * (N2 / 64), 256, 0, stream>>>(1, w_c2a, b_c2a);
  edge_kernel<1><<<8 * (N2 / 64), 256, 0, stream>>>(b_c2b);
  final_kernel<<<BATCH, 64, 0, stream>>>(w_o1, b_o1, w_o2, b_o2, w_o3, b_o3,
                                         (float*)d_out);
}